// Round 1
// baseline (656.233 us; speedup 1.0000x reference)
//
#include <hip/hip_runtime.h>

typedef unsigned short u16;
typedef __attribute__((ext_vector_type(8))) short short8;
typedef __attribute__((ext_vector_type(4))) unsigned short u16x4;
typedef __attribute__((ext_vector_type(8))) __bf16 bf16x8;
typedef __attribute__((ext_vector_type(4))) float f32x4;

#define B_SZ 4
#define NSEQ 8192
#define DMODEL 1024
#define NHEAD 16
#define DHEAD 64
#define MROWS (B_SZ * NSEQ)          // 32768
#define QKVCOLS (3 * DMODEL)         // 3072

static __device__ __forceinline__ u16 f2bf(float f) {
  unsigned u = __builtin_bit_cast(unsigned, f);
  u += 0x7fffu + ((u >> 16) & 1u);
  return (u16)(u >> 16);
}
static __device__ __forceinline__ float bf2f(u16 h) {
  return __builtin_bit_cast(float, ((unsigned)h) << 16);
}

// ---------------- fp32 -> bf16 convert ----------------
__global__ __launch_bounds__(256) void k_convert(const float* __restrict__ in,
                                                 u16* __restrict__ out, long n) {
  long i = ((long)blockIdx.x * 256 + threadIdx.x) * 4;
  if (i + 3 >= n + 4) return;
  f32x4 v = *(const f32x4*)(in + i);
  u16x4 o;
  o[0] = f2bf(v[0]); o[1] = f2bf(v[1]); o[2] = f2bf(v[2]); o[3] = f2bf(v[3]);
  *(u16x4*)(out + i) = o;
}

// ---------------- transpose fp32[R][C] -> bf16[C][R] ----------------
__global__ __launch_bounds__(256) void k_transpose(const float* __restrict__ in,
                                                   u16* __restrict__ out, int R, int C) {
  __shared__ float tile[32][33];
  int c0 = blockIdx.x * 32, r0 = blockIdx.y * 32;
  int tx = threadIdx.x, ty = threadIdx.y;  // (32, 8)
#pragma unroll
  for (int j = 0; j < 32; j += 8)
    tile[ty + j][tx] = in[(long)(r0 + ty + j) * C + c0 + tx];
  __syncthreads();
#pragma unroll
  for (int j = 0; j < 32; j += 8)
    out[(long)(c0 + ty + j) * R + r0 + tx] = f2bf(tile[tx][ty + j]);
}

// ---------------- bf16 GEMM: C[M][N] = A[M][K] * B^T[N][K] ----------------
// MODE 0: store bf16. MODE 1: store fp32 + bias.
template <int MODE>
__global__ __launch_bounds__(256) void k_gemm_bt(const u16* __restrict__ A,
                                                 const u16* __restrict__ B,
                                                 const float* __restrict__ bias,
                                                 u16* __restrict__ Cb,
                                                 float* __restrict__ Cf,
                                                 int M, int N, int K, int ldc) {
  __shared__ __align__(16) u16 As[128 * 32];
  __shared__ __align__(16) u16 Bs[128 * 32];
  const int t = threadIdx.x;
  const int lane = t & 63;
  const int w = t >> 6;
  const int wm = w >> 1, wn = w & 1;
  const long bm = blockIdx.x, bn = blockIdx.y;

  f32x4 acc[4][4] = {};

  const u16* Ag = A + bm * 128 * (long)K;
  const u16* Bg = B + bn * 128 * (long)K;
  const int r0 = t >> 2;             // 0..63
  const int s0 = (t & 3) * 8;        // col offset in bf16 elems
  const int ko = (lane >> 4) * 8;
  const int lr = lane & 15;

  for (int kt = 0; kt < K; kt += 32) {
    short8 a0 = *(const short8*)(Ag + (long)r0 * K + kt + s0);
    short8 a1 = *(const short8*)(Ag + (long)(r0 + 64) * K + kt + s0);
    short8 b0 = *(const short8*)(Bg + (long)r0 * K + kt + s0);
    short8 b1 = *(const short8*)(Bg + (long)(r0 + 64) * K + kt + s0);
    __syncthreads();
    *(short8*)(As + r0 * 32 + s0) = a0;
    *(short8*)(As + (r0 + 64) * 32 + s0) = a1;
    *(short8*)(Bs + r0 * 32 + s0) = b0;
    *(short8*)(Bs + (r0 + 64) * 32 + s0) = b1;
    __syncthreads();
    bf16x8 af[4], bfr[4];
#pragma unroll
    for (int m = 0; m < 4; ++m)
      af[m] = *(const bf16x8*)(As + (wm * 64 + m * 16 + lr) * 32 + ko);
#pragma unroll
    for (int n = 0; n < 4; ++n)
      bfr[n] = *(const bf16x8*)(Bs + (wn * 64 + n * 16 + lr) * 32 + ko);
#pragma unroll
    for (int m = 0; m < 4; ++m)
#pragma unroll
      for (int n = 0; n < 4; ++n)
        acc[m][n] = __builtin_amdgcn_mfma_f32_16x16x32_bf16(af[m], bfr[n], acc[m][n], 0, 0, 0);
  }

  const int row_base = (int)bm * 128 + wm * 64 + (lane >> 4) * 4;
  const int col_base = (int)bn * 128 + wn * 64 + lr;
#pragma unroll
  for (int m = 0; m < 4; ++m)
#pragma unroll
    for (int n = 0; n < 4; ++n)
#pragma unroll
      for (int r = 0; r < 4; ++r) {
        int row = row_base + m * 16 + r;
        int col = col_base + n * 16;
        if (MODE == 0)
          Cb[(long)row * ldc + col] = f2bf(acc[m][n][r]);
        else
          Cf[(long)row * ldc + col] = acc[m][n][r] + bias[col];
      }
}

// ---------------- q softmax over each 64-wide head segment ----------------
__global__ __launch_bounds__(256) void k_qsoftmax(u16* __restrict__ qkv) {
  const int lane = threadIdx.x & 63;
  const int wblk = threadIdx.x >> 6;
  const long gw = (long)blockIdx.x * 4 + wblk;  // 8192 waves
  const int sub = lane >> 4;
  const int pos = (lane & 15) * 4;
  for (int it = 0; it < 16; ++it) {
    long g = gw * 16 + it;          // group of 4 segments
    long seg = g * 4 + sub;
    long row = seg >> 4;
    int h = (int)(seg & 15);
    u16* p = qkv + row * QKVCOLS + h * 64 + pos;
    u16x4 v = *(const u16x4*)p;
    float f0 = bf2f(v[0]) * 0.125f, f1 = bf2f(v[1]) * 0.125f;
    float f2 = bf2f(v[2]) * 0.125f, f3 = bf2f(v[3]) * 0.125f;
    float m = fmaxf(fmaxf(f0, f1), fmaxf(f2, f3));
#pragma unroll
    for (int off = 1; off < 16; off <<= 1) m = fmaxf(m, __shfl_xor(m, off));
    float p0 = __expf(f0 - m), p1 = __expf(f1 - m);
    float p2 = __expf(f2 - m), p3 = __expf(f3 - m);
    float s = p0 + p1 + p2 + p3;
#pragma unroll
    for (int off = 1; off < 16; off <<= 1) s += __shfl_xor(s, off);
    float inv = 1.0f / s;
    u16x4 o;
    o[0] = f2bf(p0 * inv); o[1] = f2bf(p1 * inv);
    o[2] = f2bf(p2 * inv); o[3] = f2bf(p3 * inv);
    *(u16x4*)p = o;
  }
}

// ---------------- k exp + column sums ----------------
__global__ __launch_bounds__(256) void k_kexp(u16* __restrict__ qkv, float* __restrict__ S) {
  int c = blockIdx.x * 256 + threadIdx.x;   // 0..1023
  int b = blockIdx.z;
  int r0 = blockIdx.y * 128;
  u16* base = qkv + ((long)(b * NSEQ + r0)) * QKVCOLS + DMODEL + c;
  float sum = 0.f;
#pragma unroll 4
  for (int r = 0; r < 128; ++r) {
    float v = __expf(bf2f(*base));
    *base = f2bf(v);
    sum += v;
    base += QKVCOLS;
  }
  atomicAdd(&S[b * DMODEL + c], sum);
}

// ---------------- context partial: ctx[bh][d][e] += sum_n q[n][d]*k[n][e] ----------------
__global__ __launch_bounds__(256) void k_ctx(const u16* __restrict__ qkv, float* __restrict__ ctx) {
  __shared__ float qs[64][64];
  __shared__ float ks[64][64];
  const int bh = blockIdx.x;
  const int b = bh >> 4, h = bh & 15;
  const int t = threadIdx.x;
  const int td = t & 15, te = t >> 4;
  float acc[4][4] = {};
  const long rowbase = (long)b * NSEQ + (long)blockIdx.y * 512;
  const u16* qbase = qkv + rowbase * QKVCOLS + h * 64;
  const u16* kbase = qkv + rowbase * QKVCOLS + DMODEL + h * 64;
  const int slr = t >> 2;            // 0..63
  const int slc = (t & 3) * 16;      // 0,16,32,48
  for (int st = 0; st < 8; ++st) {
    __syncthreads();
    const u16* qg = qbase + (long)(st * 64 + slr) * QKVCOLS + slc;
    const u16* kg = kbase + (long)(st * 64 + slr) * QKVCOLS + slc;
    short8 q0 = *(const short8*)qg, q1 = *(const short8*)(qg + 8);
    short8 kk0 = *(const short8*)kg, kk1 = *(const short8*)(kg + 8);
#pragma unroll
    for (int j = 0; j < 8; ++j) {
      qs[slr][slc + j] = bf2f((u16)q0[j]);
      qs[slr][slc + 8 + j] = bf2f((u16)q1[j]);
      ks[slr][slc + j] = bf2f((u16)kk0[j]);
      ks[slr][slc + 8 + j] = bf2f((u16)kk1[j]);
    }
    __syncthreads();
#pragma unroll 8
    for (int rr = 0; rr < 64; ++rr) {
      f32x4 qf = *(const f32x4*)&qs[rr][td * 4];
      f32x4 kf = *(const f32x4*)&ks[rr][te * 4];
#pragma unroll
      for (int i = 0; i < 4; ++i)
#pragma unroll
        for (int j = 0; j < 4; ++j)
          acc[i][j] += qf[i] * kf[j];
    }
  }
#pragma unroll
  for (int i = 0; i < 4; ++i)
#pragma unroll
    for (int j = 0; j < 4; ++j)
      atomicAdd(&ctx[((long)bh * 64 + td * 4 + i) * 64 + te * 4 + j], acc[i][j]);
}

// ---------------- normalize + transpose context ----------------
__global__ __launch_bounds__(256) void k_ctxnorm(const float* __restrict__ ctx,
                                                 const float* __restrict__ S,
                                                 u16* __restrict__ ctxT) {
  int bh = blockIdx.x;
  int b = bh >> 4, h = bh & 15;
  for (int i = threadIdx.x; i < 4096; i += 256) {
    int d = i >> 6, e = i & 63;
    float v = ctx[(long)bh * 4096 + i] / S[b * DMODEL + h * 64 + e];
    ctxT[(long)bh * 4096 + e * 64 + d] = f2bf(v);
  }
}

// ---------------- out_attn[n][h*64+e] = sum_d v[n][d] * ctx[d][e] ----------------
__global__ __launch_bounds__(256) void k_pv(const u16* __restrict__ qkv,
                                            const u16* __restrict__ ctxT,
                                            u16* __restrict__ oattn) {
  __shared__ __align__(16) u16 cs[64 * 64];
  const int bh = blockIdx.y;
  const int b = bh >> 4, h = bh & 15;
  const int t = threadIdx.x, lane = t & 63, w = t >> 6;
  {
    int i = t * 16;
    *(short8*)(cs + i) = *(const short8*)(ctxT + (long)bh * 4096 + i);
    *(short8*)(cs + i + 8) = *(const short8*)(ctxT + (long)bh * 4096 + i + 8);
  }
  __syncthreads();
  const long r0 = (long)blockIdx.x * 256 + w * 64;
  const u16* vbase = qkv + ((long)b * NSEQ + r0) * QKVCOLS + 2 * DMODEL + h * 64;
  f32x4 acc[4][4] = {};
  const int ko = (lane >> 4) * 8;
  const int lr = lane & 15;
#pragma unroll
  for (int ks = 0; ks < 2; ++ks) {
    bf16x8 af[4], bfr[4];
#pragma unroll
    for (int m = 0; m < 4; ++m)
      af[m] = *(const bf16x8*)(vbase + (long)(m * 16 + lr) * QKVCOLS + ks * 32 + ko);
#pragma unroll
    for (int n = 0; n < 4; ++n)
      bfr[n] = *(const bf16x8*)(cs + (n * 16 + lr) * 64 + ks * 32 + ko);
#pragma unroll
    for (int m = 0; m < 4; ++m)
#pragma unroll
      for (int n = 0; n < 4; ++n)
        acc[m][n] = __builtin_amdgcn_mfma_f32_16x16x32_bf16(af[m], bfr[n], acc[m][n], 0, 0, 0);
  }
#pragma unroll
  for (int m = 0; m < 4; ++m)
#pragma unroll
    for (int n = 0; n < 4; ++n)
#pragma unroll
      for (int r = 0; r < 4; ++r) {
        long row = r0 + m * 16 + (lane >> 4) * 4 + r;
        int col = h * 64 + n * 16 + lr;
        oattn[((long)b * NSEQ + row) * DMODEL + col] = f2bf(acc[m][n][r]);
      }
}

// ---------------- launch ----------------
extern "C" void kernel_launch(void* const* d_in, const int* in_sizes, int n_in,
                              void* d_out, int out_size, void* d_ws, size_t ws_size,
                              hipStream_t stream) {
  const float* x = (const float*)d_in[0];
  const float* w_qkv = (const float*)d_in[1];
  const float* w_out = (const float*)d_in[2];
  const float* b_out = (const float*)d_in[3];
  float* out = (float*)d_out;
  char* ws = (char*)d_ws;

  u16* xb     = (u16*)(ws + 0);                 // 64 MB
  u16* wqkvT  = (u16*)(ws + 67108864L);         // 6 MB
  u16* woutT  = (u16*)(ws + 73400320L);         // 2 MB
  u16* qkv    = (u16*)(ws + 75497472L);         // 192 MB
  u16* oattn  = (u16*)(ws + 276824064L);        // 64 MB
  float* S    = (float*)(ws + 343932928L);      // 16 KB
  float* ctx  = (float*)(ws + 343949312L);      // 1 MB
  u16* ctxT   = (u16*)(ws + 344997888L);        // 0.5 MB

  hipMemsetAsync(S, 0, 16384 + 1048576, stream);

  k_convert<<<32768, 256, 0, stream>>>(x, xb, (long)MROWS * DMODEL);
  k_transpose<<<dim3(96, 32), dim3(32, 8), 0, stream>>>(w_qkv, wqkvT, DMODEL, QKVCOLS);
  k_transpose<<<dim3(32, 32), dim3(32, 8), 0, stream>>>(w_out, woutT, DMODEL, DMODEL);

  k_gemm_bt<0><<<dim3(MROWS / 128, QKVCOLS / 128), 256, 0, stream>>>(
      xb, wqkvT, nullptr, qkv, nullptr, MROWS, QKVCOLS, DMODEL, QKVCOLS);

  k_qsoftmax<<<2048, 256, 0, stream>>>(qkv);
  k_kexp<<<dim3(4, 64, 4), 256, 0, stream>>>(qkv, S);
  k_ctx<<<dim3(64, 16), 256, 0, stream>>>(qkv, ctx);
  k_ctxnorm<<<64, 256, 0, stream>>>(ctx, S, ctxT);
  k_pv<<<dim3(32, 64), 256, 0, stream>>>(qkv, ctxT, oattn);

  k_gemm_bt<1><<<dim3(MROWS / 128, DMODEL / 128), 256, 0, stream>>>(
      oattn, woutT, b_out, nullptr, out, MROWS, DMODEL, DMODEL, DMODEL);
}

// Round 2
// 582.612 us; speedup vs baseline: 1.1264x; 1.1264x over previous
//
#include <hip/hip_runtime.h>

typedef unsigned short u16;
typedef __attribute__((ext_vector_type(8))) short short8;
typedef __attribute__((ext_vector_type(4))) unsigned short u16x4;
typedef __attribute__((ext_vector_type(8))) __bf16 bf16x8;
typedef __attribute__((ext_vector_type(4))) float f32x4;

#define B_SZ 4
#define NSEQ 8192
#define DMODEL 1024
#define NHEAD 16
#define DHEAD 64
#define MROWS (B_SZ * NSEQ)          // 32768
#define QKVCOLS (3 * DMODEL)         // 3072

static __device__ __forceinline__ u16 f2bf(float f) {
  unsigned u = __builtin_bit_cast(unsigned, f);
  u += 0x7fffu + ((u >> 16) & 1u);
  return (u16)(u >> 16);
}
static __device__ __forceinline__ float bf2f(u16 h) {
  return __builtin_bit_cast(float, ((unsigned)h) << 16);
}

static __device__ __forceinline__ void gload16(const u16* g, u16* l) {
  __builtin_amdgcn_global_load_lds(
      (const __attribute__((address_space(1))) unsigned*)g,
      (__attribute__((address_space(3))) unsigned*)l, 16, 0, 0);
}

// ---------------- fp32 -> bf16 convert ----------------
__global__ __launch_bounds__(256) void k_convert(const float* __restrict__ in,
                                                 u16* __restrict__ out, long n) {
  long i = ((long)blockIdx.x * 256 + threadIdx.x) * 4;
  if (i >= n) return;
  f32x4 v = *(const f32x4*)(in + i);
  u16x4 o;
  o[0] = f2bf(v[0]); o[1] = f2bf(v[1]); o[2] = f2bf(v[2]); o[3] = f2bf(v[3]);
  *(u16x4*)(out + i) = o;
}

// ---------------- transpose fp32[R][C] -> bf16[C][R] ----------------
__global__ __launch_bounds__(256) void k_transpose(const float* __restrict__ in,
                                                   u16* __restrict__ out, int R, int C) {
  __shared__ float tile[32][33];
  int c0 = blockIdx.x * 32, r0 = blockIdx.y * 32;
  int tx = threadIdx.x, ty = threadIdx.y;  // (32, 8)
#pragma unroll
  for (int j = 0; j < 32; j += 8)
    tile[ty + j][tx] = in[(long)(r0 + ty + j) * C + c0 + tx];
  __syncthreads();
#pragma unroll
  for (int j = 0; j < 32; j += 8)
    out[(long)(c0 + ty + j) * R + r0 + tx] = f2bf(tile[tx][ty + j]);
}

// ---------------- bf16 GEMM (m97 structure): C[M][N] = A[M][K] * B^T[N][K] ----
// EPI 0: qkv fused epilogue (bn<8: q-softmax; bn<16: k-exp+colsum; else v store)
// EPI 1: fp32 + bias store
template <int EPI>
__global__ __launch_bounds__(256) void k_gemm_lds(
    const u16* __restrict__ A, const u16* __restrict__ B,
    const float* __restrict__ bias, u16* __restrict__ Cb,
    float* __restrict__ Cf, float* __restrict__ S,
    int K, int nbn, int ldc) {
  __shared__ __align__(16) u16 As[128 * 32];
  __shared__ __align__(16) u16 Bs[128 * 32];
  const int t = threadIdx.x;
  const int lane = t & 63;
  const int w = t >> 6;
  const int wm = w >> 1, wn = w & 1;

  // XCD swizzle (grid % 8 == 0 in both uses) + bm-group-of-8 ordering
  const int nwg = gridDim.x;
  const int bid = blockIdx.x;
  const int swz = (bid & 7) * (nwg >> 3) + (bid >> 3);
  const int per = 8 * nbn;
  const int grp = swz / per, rem = swz % per;
  const int bm = grp * 8 + (rem & 7);
  const int bn = rem / 8;

  const u16* Ag = A + (long)bm * 128 * K;
  const u16* Bg = B + (long)bn * 128 * K;
  // staging: wave w loads rows [w*16, w*16+16) and [64+w*16, ...) of each tile
  const int grow = lane >> 2;          // 0..15
  const int gcol = (lane & 3) * 8;     // element offset in K
  u16* as0 = As + (w * 16) * 32;
  u16* as1 = As + (64 + w * 16) * 32;
  u16* bs0 = Bs + (w * 16) * 32;
  u16* bs1 = Bs + (64 + w * 16) * 32;
  const long off0 = (long)(w * 16 + grow) * K + gcol;
  const long off1 = (long)(64 + w * 16 + grow) * K + gcol;

  const int ko = (lane >> 4) * 8;
  const int lr = lane & 15;
  f32x4 acc[4][4] = {};

  for (int kt = 0; kt < K; kt += 32) {
    gload16(Ag + off0 + kt, as0);
    gload16(Ag + off1 + kt, as1);
    gload16(Bg + off0 + kt, bs0);
    gload16(Bg + off1 + kt, bs1);
    __syncthreads();   // drains vmcnt -> LDS tiles ready
    bf16x8 af[4], bfr[4];
#pragma unroll
    for (int m = 0; m < 4; ++m)
      af[m] = *(const bf16x8*)(As + (wm * 64 + m * 16 + lr) * 32 + ko);
#pragma unroll
    for (int n = 0; n < 4; ++n)
      bfr[n] = *(const bf16x8*)(Bs + (wn * 64 + n * 16 + lr) * 32 + ko);
#pragma unroll
    for (int m = 0; m < 4; ++m)
#pragma unroll
      for (int n = 0; n < 4; ++n)
        acc[m][n] = __builtin_amdgcn_mfma_f32_16x16x32_bf16(af[m], bfr[n], acc[m][n], 0, 0, 0);
    __syncthreads();   // all reads done before next stage overwrites
  }

  const int row_base = bm * 128 + wm * 64 + (lane >> 4) * 4;
  const int col_base = bn * 128 + wn * 64 + lr;

  if (EPI == 1) {
#pragma unroll
    for (int m = 0; m < 4; ++m)
#pragma unroll
      for (int n = 0; n < 4; ++n)
#pragma unroll
        for (int r = 0; r < 4; ++r)
          Cf[(long)(row_base + m * 16 + r) * ldc + col_base + n * 16] =
              acc[m][n][r] + bias[col_base + n * 16];
    return;
  }

  if (bn < 8) {
    // q: softmax over this wave's 64-col head segment, per output row
#pragma unroll
    for (int m = 0; m < 4; ++m)
#pragma unroll
      for (int r = 0; r < 4; ++r) {
        float p[4];
        float mx = -1e30f;
#pragma unroll
        for (int n = 0; n < 4; ++n) {
          p[n] = acc[m][n][r] * 0.125f;
          mx = fmaxf(mx, p[n]);
        }
#pragma unroll
        for (int off = 1; off < 16; off <<= 1) mx = fmaxf(mx, __shfl_xor(mx, off));
        float s = 0.f;
#pragma unroll
        for (int n = 0; n < 4; ++n) { p[n] = __expf(p[n] - mx); s += p[n]; }
#pragma unroll
        for (int off = 1; off < 16; off <<= 1) s += __shfl_xor(s, off);
        float inv = 1.0f / s;
        long row = row_base + m * 16 + r;
#pragma unroll
        for (int n = 0; n < 4; ++n)
          Cb[row * ldc + col_base + n * 16] = f2bf(p[n] * inv);
      }
  } else if (bn < 16) {
    // k: exp + per-batch column sums
    float cs[4] = {0.f, 0.f, 0.f, 0.f};
#pragma unroll
    for (int m = 0; m < 4; ++m)
#pragma unroll
      for (int n = 0; n < 4; ++n)
#pragma unroll
        for (int r = 0; r < 4; ++r) {
          float p = __expf(acc[m][n][r]);
          cs[n] += p;
          Cb[(long)(row_base + m * 16 + r) * ldc + col_base + n * 16] = f2bf(p);
        }
#pragma unroll
    for (int n = 0; n < 4; ++n) {
      cs[n] += __shfl_xor(cs[n], 16);
      cs[n] += __shfl_xor(cs[n], 32);
    }
    if (lane < 16) {
      int b = bm >> 6;  // 64 row-tiles per batch
#pragma unroll
      for (int n = 0; n < 4; ++n)
        atomicAdd(&S[b * DMODEL + (bn - 8) * 128 + wn * 64 + n * 16 + lane], cs[n]);
    }
  } else {
    // v: plain bf16 store
#pragma unroll
    for (int m = 0; m < 4; ++m)
#pragma unroll
      for (int n = 0; n < 4; ++n)
#pragma unroll
        for (int r = 0; r < 4; ++r)
          Cb[(long)(row_base + m * 16 + r) * ldc + col_base + n * 16] = f2bf(acc[m][n][r]);
  }
}

// ---------------- context partial: ctx[bh][d][e] += sum_n q[n][d]*k[n][e] ----------------
__global__ __launch_bounds__(256) void k_ctx(const u16* __restrict__ qkv, float* __restrict__ ctx) {
  __shared__ float qs[64][64];
  __shared__ float ks[64][64];
  const int bh = blockIdx.x;
  const int b = bh >> 4, h = bh & 15;
  const int t = threadIdx.x;
  const int td = t & 15, te = t >> 4;
  float acc[4][4] = {};
  const long rowbase = (long)b * NSEQ + (long)blockIdx.y * 512;
  const u16* qbase = qkv + rowbase * QKVCOLS + h * 64;
  const u16* kbase = qkv + rowbase * QKVCOLS + DMODEL + h * 64;
  const int slr = t >> 2;            // 0..63
  const int slc = (t & 3) * 16;      // 0,16,32,48
  for (int st = 0; st < 8; ++st) {
    __syncthreads();
    const u16* qg = qbase + (long)(st * 64 + slr) * QKVCOLS + slc;
    const u16* kg = kbase + (long)(st * 64 + slr) * QKVCOLS + slc;
    short8 q0 = *(const short8*)qg, q1 = *(const short8*)(qg + 8);
    short8 kk0 = *(const short8*)kg, kk1 = *(const short8*)(kg + 8);
#pragma unroll
    for (int j = 0; j < 8; ++j) {
      qs[slr][slc + j] = bf2f((u16)q0[j]);
      qs[slr][slc + 8 + j] = bf2f((u16)q1[j]);
      ks[slr][slc + j] = bf2f((u16)kk0[j]);
      ks[slr][slc + 8 + j] = bf2f((u16)kk1[j]);
    }
    __syncthreads();
#pragma unroll 8
    for (int rr = 0; rr < 64; ++rr) {
      f32x4 qf = *(const f32x4*)&qs[rr][td * 4];
      f32x4 kf = *(const f32x4*)&ks[rr][te * 4];
#pragma unroll
      for (int i = 0; i < 4; ++i)
#pragma unroll
        for (int j = 0; j < 4; ++j)
          acc[i][j] += qf[i] * kf[j];
    }
  }
#pragma unroll
  for (int i = 0; i < 4; ++i)
#pragma unroll
    for (int j = 0; j < 4; ++j)
      atomicAdd(&ctx[((long)bh * 64 + td * 4 + i) * 64 + te * 4 + j], acc[i][j]);
}

// ---------------- normalize + transpose context ----------------
__global__ __launch_bounds__(256) void k_ctxnorm(const float* __restrict__ ctx,
                                                 const float* __restrict__ S,
                                                 u16* __restrict__ ctxT) {
  int bh = blockIdx.x;
  int b = bh >> 4, h = bh & 15;
  for (int i = threadIdx.x; i < 4096; i += 256) {
    int d = i >> 6, e = i & 63;
    float v = ctx[(long)bh * 4096 + i] / S[b * DMODEL + h * 64 + e];
    ctxT[(long)bh * 4096 + e * 64 + d] = f2bf(v);
  }
}

// ---------------- out_attn[n][h*64+e] = sum_d v[n][d] * ctx[d][e] ----------------
__global__ __launch_bounds__(256) void k_pv(const u16* __restrict__ qkv,
                                            const u16* __restrict__ ctxT,
                                            u16* __restrict__ oattn) {
  __shared__ __align__(16) u16 cs[64 * 64];
  const int bh = blockIdx.y;
  const int b = bh >> 4, h = bh & 15;
  const int t = threadIdx.x, lane = t & 63, w = t >> 6;
  {
    int i = t * 16;
    *(short8*)(cs + i) = *(const short8*)(ctxT + (long)bh * 4096 + i);
    *(short8*)(cs + i + 8) = *(const short8*)(ctxT + (long)bh * 4096 + i + 8);
  }
  __syncthreads();
  const long r0 = (long)blockIdx.x * 256 + w * 64;
  const u16* vbase = qkv + ((long)b * NSEQ + r0) * QKVCOLS + 2 * DMODEL + h * 64;
  f32x4 acc[4][4] = {};
  const int ko = (lane >> 4) * 8;
  const int lr = lane & 15;
#pragma unroll
  for (int ks = 0; ks < 2; ++ks) {
    bf16x8 af[4], bfr[4];
#pragma unroll
    for (int m = 0; m < 4; ++m)
      af[m] = *(const bf16x8*)(vbase + (long)(m * 16 + lr) * QKVCOLS + ks * 32 + ko);
#pragma unroll
    for (int n = 0; n < 4; ++n)
      bfr[n] = *(const bf16x8*)(cs + (n * 16 + lr) * 64 + ks * 32 + ko);
#pragma unroll
    for (int m = 0; m < 4; ++m)
#pragma unroll
      for (int n = 0; n < 4; ++n)
        acc[m][n] = __builtin_amdgcn_mfma_f32_16x16x32_bf16(af[m], bfr[n], acc[m][n], 0, 0, 0);
  }
#pragma unroll
  for (int m = 0; m < 4; ++m)
#pragma unroll
    for (int n = 0; n < 4; ++n)
#pragma unroll
      for (int r = 0; r < 4; ++r) {
        long row = r0 + m * 16 + (lane >> 4) * 4 + r;
        int col = h * 64 + n * 16 + lr;
        oattn[((long)b * NSEQ + row) * DMODEL + col] = f2bf(acc[m][n][r]);
      }
}

// ---------------- launch ----------------
extern "C" void kernel_launch(void* const* d_in, const int* in_sizes, int n_in,
                              void* d_out, int out_size, void* d_ws, size_t ws_size,
                              hipStream_t stream) {
  const float* x = (const float*)d_in[0];
  const float* w_qkv = (const float*)d_in[1];
  const float* w_out = (const float*)d_in[2];
  const float* b_out = (const float*)d_in[3];
  float* out = (float*)d_out;
  char* ws = (char*)d_ws;

  u16* xb     = (u16*)(ws + 0);                 // 64 MB
  u16* wqkvT  = (u16*)(ws + 67108864L);         // 6 MB
  u16* woutT  = (u16*)(ws + 73400320L);         // 2 MB
  u16* qkv    = (u16*)(ws + 75497472L);         // 192 MB
  u16* oattn  = (u16*)(ws + 276824064L);        // 64 MB
  float* S    = (float*)(ws + 343932928L);      // 16 KB
  float* ctx  = (float*)(ws + 343949312L);      // 1 MB
  u16* ctxT   = (u16*)(ws + 344997888L);        // 0.5 MB

  hipMemsetAsync(S, 0, 16384 + 1048576, stream);

  k_convert<<<32768, 256, 0, stream>>>(x, xb, (long)MROWS * DMODEL);
  k_transpose<<<dim3(96, 32), dim3(32, 8), 0, stream>>>(w_qkv, wqkvT, DMODEL, QKVCOLS);
  k_transpose<<<dim3(32, 32), dim3(32, 8), 0, stream>>>(w_out, woutT, DMODEL, DMODEL);

  // qkv GEMM with fused q-softmax / k-exp epilogue
  k_gemm_lds<0><<<dim3((MROWS / 128) * (QKVCOLS / 128)), 256, 0, stream>>>(
      xb, wqkvT, nullptr, qkv, nullptr, S, DMODEL, QKVCOLS / 128, QKVCOLS);

  k_ctx<<<dim3(64, 16), 256, 0, stream>>>(qkv, ctx);
  k_ctxnorm<<<64, 256, 0, stream>>>(ctx, S, ctxT);
  k_pv<<<dim3(32, 64), 256, 0, stream>>>(qkv, ctxT, oattn);

  k_gemm_lds<1><<<dim3((MROWS / 128) * (DMODEL / 128)), 256, 0, stream>>>(
      oattn, woutT, b_out, nullptr, out, nullptr, DMODEL, DMODEL / 128, DMODEL);
}

// Round 3
// 459.230 us; speedup vs baseline: 1.4290x; 1.2687x over previous
//
#include <hip/hip_runtime.h>

typedef unsigned short u16;
typedef __attribute__((ext_vector_type(8))) short short8;
typedef __attribute__((ext_vector_type(4))) unsigned short u16x4;
typedef __attribute__((ext_vector_type(8))) __bf16 bf16x8;
typedef __attribute__((ext_vector_type(4))) float f32x4;

#define B_SZ 4
#define NSEQ 8192
#define DMODEL 1024
#define MROWS 32768
#define QKVCOLS 3072

static __device__ __forceinline__ u16 f2bf(float f) {
  unsigned u = __builtin_bit_cast(unsigned, f);
  u += 0x7fffu + ((u >> 16) & 1u);
  return (u16)(u >> 16);
}
static __device__ __forceinline__ float bf2f(u16 h) {
  return __builtin_bit_cast(float, ((unsigned)h) << 16);
}
static __device__ __forceinline__ void gload16(const u16* g, u16* l) {
  __builtin_amdgcn_global_load_lds(
      (const __attribute__((address_space(1))) unsigned*)g,
      (__attribute__((address_space(3))) unsigned*)l, 16, 0, 0);
}

// ---------------- fp32 -> bf16 convert ----------------
__global__ __launch_bounds__(256) void k_convert(const float* __restrict__ in,
                                                 u16* __restrict__ out, long n) {
  long i = ((long)blockIdx.x * 256 + threadIdx.x) * 4;
  if (i >= n) return;
  f32x4 v = *(const f32x4*)(in + i);
  u16x4 o;
  o[0] = f2bf(v[0]); o[1] = f2bf(v[1]); o[2] = f2bf(v[2]); o[3] = f2bf(v[3]);
  *(u16x4*)(out + i) = o;
}

// ---------------- transpose fp32[R][C] -> bf16[C][R] ----------------
__global__ __launch_bounds__(256) void k_transpose(const float* __restrict__ in,
                                                   u16* __restrict__ out, int R, int C) {
  __shared__ float tile[32][33];
  int c0 = blockIdx.x * 32, r0 = blockIdx.y * 32;
  int tx = threadIdx.x, ty = threadIdx.y;  // (32, 8)
#pragma unroll
  for (int j = 0; j < 32; j += 8)
    tile[ty + j][tx] = in[(long)(r0 + ty + j) * C + c0 + tx];
  __syncthreads();
#pragma unroll
  for (int j = 0; j < 32; j += 8)
    out[(long)(c0 + ty + j) * R + r0 + tx] = f2bf(tile[tx][ty + j]);
}

// ============ 256x256 8-phase bf16 GEMM: C = A[M][K] * B^T[N][K] ============
// EPI 0: qkv fused epilogue (bn<4 q-softmax, bn<8 k-exp+colsum, else v store)
// EPI 1: fp32 + bias
// B-rows are staged permuted so each wave owns one contiguous 64-col segment:
//   LDS B row (Qn*128 + wn*32 + n*16 + lr)  <->  global col (wn*64 + Qn*32 + n*16 + lr)
template <int EPI>
__global__ __launch_bounds__(512, 2) void k_gemm256(
    const u16* __restrict__ A, const u16* __restrict__ B,
    const float* __restrict__ bias, u16* __restrict__ Cb,
    float* __restrict__ Cf, float* __restrict__ S,
    int K, int nbn, int ldc) {
  __shared__ __align__(16) u16 sm[65536];  // A0|A1|B0|B1, 16384 u16 each
  const int t = threadIdx.x;
  const int lane = t & 63;
  const int w = t >> 6;       // 0..7
  const int wq = w >> 2;      // row-half within quadrant
  const int wn = w & 3;       // col group
  const int lr = lane & 15;
  const int hi = lane >> 4;
  const int l3 = lane >> 3;

  // XCD swizzle + bm-group-of-8
  const int nwg = gridDim.x;
  const int bid = blockIdx.x;
  const int swz = (bid & 7) * (nwg >> 3) + (bid >> 3);
  const int per = 8 * nbn;
  const int grp = swz / per, rem = swz % per;
  const int bm = grp * 8 + (rem & 7);
  const int bn = rem / 8;

  const int gcol = ((lane & 7) ^ l3) * 8;  // swizzled k-offset (elements)

  // stage A half-tile (128 rows x 64 k) of K-tile `tile` into buffer `buf`
  auto stA = [&](int tile, int half, int buf) {
    u16* dst = &sm[buf * 16384 + (half * 128 + w * 16) * 64];
    const u16* g = A + ((long)(bm * 256 + half * 128 + w * 16 + l3)) * K + tile * 64 + gcol;
    gload16(g, dst);
    gload16(g + 8 * (long)K, dst + 8 * 64);
  };
  auto stB = [&](int tile, int half, int buf) {
#pragma unroll
    for (int L = 0; L < 2; ++L) {
      int base = half * 128 + w * 16 + L * 8;  // LDS B row base
      int grow = bn * 256 + ((base >> 5) & 3) * 64 + half * 32 + (base & 31) + l3;
      const u16* g = B + (long)grow * K + tile * 64 + gcol;
      gload16(g, &sm[32768 + buf * 16384 + base * 64]);
    }
  };

  const int su = (lr & 7) << 3;
  const int cu0 = (hi * 8) ^ su;         // kk=0 swizzled col (u16 units)
  const int cu1 = (32 + hi * 8) ^ su;    // kk=1
  const int arow = wq * 64 + lr;
  const int brow = wn * 32 + lr;

  auto ldA = [&](int buf, int Qm, int m, int kk) -> bf16x8 {
    return *(const bf16x8*)&sm[buf * 16384 + (Qm * 128 + arow + m * 16) * 64 + (kk ? cu1 : cu0)];
  };
  auto ldB = [&](int buf, int Qn, int n, int kk) -> bf16x8 {
    return *(const bf16x8*)&sm[32768 + buf * 16384 + (Qn * 128 + brow + n * 16) * 64 + (kk ? cu1 : cu0)];
  };

  f32x4 acc[2][2][4][2] = {};
  bf16x8 af[4][2], bl[2][2], bh[2][2];
  const int NT = K >> 6;

  // prologue: tile0 full + Alo/Blo/Bhi of tile1; leave 3 half-tiles in flight
  stA(0, 0, 0); stB(0, 0, 0); stB(0, 1, 0); stA(0, 1, 0);
  stA(1, 0, 1); stB(1, 0, 1); stB(1, 1, 1);
  asm volatile("s_waitcnt vmcnt(6)" ::: "memory");
  __builtin_amdgcn_s_barrier();

  for (int tt = 0; tt < NT; ++tt) {
    const int p = tt & 1;
    const int c1 = (tt + 1 < NT) ? tt + 1 : NT - 1;
    const int c2 = (tt + 2 < NT) ? tt + 2 : NT - 1;
    // ---- P1: quadrant (0,0) ----
#pragma unroll
    for (int m = 0; m < 4; ++m) { af[m][0] = ldA(p, 0, m, 0); af[m][1] = ldA(p, 0, m, 1); }
#pragma unroll
    for (int n = 0; n < 2; ++n) { bl[n][0] = ldB(p, 0, n, 0); bl[n][1] = ldB(p, 0, n, 1); }
    stA(c1, 1, (tt + 1) & 1);
    __builtin_amdgcn_s_barrier();
    asm volatile("s_waitcnt lgkmcnt(0)" ::: "memory");
    __builtin_amdgcn_sched_barrier(0);
    __builtin_amdgcn_s_setprio(1);
#pragma unroll
    for (int m = 0; m < 4; ++m)
#pragma unroll
      for (int n = 0; n < 2; ++n)
        acc[0][0][m][n] = __builtin_amdgcn_mfma_f32_16x16x32_bf16(af[m][1], bl[n][1],
            __builtin_amdgcn_mfma_f32_16x16x32_bf16(af[m][0], bl[n][0], acc[0][0][m][n], 0, 0, 0), 0, 0, 0);
    __builtin_amdgcn_s_setprio(0);
    __builtin_amdgcn_s_barrier();
    // ---- P2: quadrant (0,1) ----
#pragma unroll
    for (int n = 0; n < 2; ++n) { bh[n][0] = ldB(p, 1, n, 0); bh[n][1] = ldB(p, 1, n, 1); }
    stA(c2, 0, p);
    __builtin_amdgcn_s_barrier();
    asm volatile("s_waitcnt lgkmcnt(0)" ::: "memory");
    __builtin_amdgcn_sched_barrier(0);
    __builtin_amdgcn_s_setprio(1);
#pragma unroll
    for (int m = 0; m < 4; ++m)
#pragma unroll
      for (int n = 0; n < 2; ++n)
        acc[0][1][m][n] = __builtin_amdgcn_mfma_f32_16x16x32_bf16(af[m][1], bh[n][1],
            __builtin_amdgcn_mfma_f32_16x16x32_bf16(af[m][0], bh[n][0], acc[0][1][m][n], 0, 0, 0), 0, 0, 0);
    __builtin_amdgcn_s_setprio(0);
    __builtin_amdgcn_s_barrier();
    // ---- P3: quadrant (1,1) ----
#pragma unroll
    for (int m = 0; m < 4; ++m) { af[m][0] = ldA(p, 1, m, 0); af[m][1] = ldA(p, 1, m, 1); }
    stB(c2, 0, p);
    __builtin_amdgcn_s_barrier();
    asm volatile("s_waitcnt lgkmcnt(0)" ::: "memory");
    __builtin_amdgcn_sched_barrier(0);
    __builtin_amdgcn_s_setprio(1);
#pragma unroll
    for (int m = 0; m < 4; ++m)
#pragma unroll
      for (int n = 0; n < 2; ++n)
        acc[1][1][m][n] = __builtin_amdgcn_mfma_f32_16x16x32_bf16(af[m][1], bh[n][1],
            __builtin_amdgcn_mfma_f32_16x16x32_bf16(af[m][0], bh[n][0], acc[1][1][m][n], 0, 0, 0), 0, 0, 0);
    __builtin_amdgcn_s_setprio(0);
    __builtin_amdgcn_s_barrier();
    // ---- P4: quadrant (1,0) ----
    stB(c2, 1, p);
    __builtin_amdgcn_s_barrier();
    __builtin_amdgcn_s_setprio(1);
#pragma unroll
    for (int m = 0; m < 4; ++m)
#pragma unroll
      for (int n = 0; n < 2; ++n)
        acc[1][0][m][n] = __builtin_amdgcn_mfma_f32_16x16x32_bf16(af[m][1], bl[n][1],
            __builtin_amdgcn_mfma_f32_16x16x32_bf16(af[m][0], bl[n][0], acc[1][0][m][n], 0, 0, 0), 0, 0, 0);
    __builtin_amdgcn_s_setprio(0);
    asm volatile("s_waitcnt vmcnt(6)" ::: "memory");
    __builtin_amdgcn_s_barrier();
  }

  // ---------------- epilogue ----------------
  const int row0 = bm * 256 + wq * 64 + hi * 4;
  const int colw = bn * 256 + wn * 64;

  if (EPI == 1) {
#pragma unroll
    for (int Qm = 0; Qm < 2; ++Qm)
#pragma unroll
      for (int m = 0; m < 4; ++m)
#pragma unroll
        for (int r = 0; r < 4; ++r) {
          long row = row0 + Qm * 128 + m * 16 + r;
#pragma unroll
          for (int Qn = 0; Qn < 2; ++Qn)
#pragma unroll
            for (int n = 0; n < 2; ++n) {
              int col = colw + Qn * 32 + n * 16 + lr;
              Cf[row * ldc + col] = acc[Qm][Qn][m][n][r] + bias[col];
            }
        }
    return;
  }

  if (bn < 4) {
    // q: softmax over the wave's 64-col head segment, per row
#pragma unroll
    for (int Qm = 0; Qm < 2; ++Qm)
#pragma unroll
      for (int m = 0; m < 4; ++m)
#pragma unroll
        for (int r = 0; r < 4; ++r) {
          float pv[2][2];
          float mx = -1e30f;
#pragma unroll
          for (int Qn = 0; Qn < 2; ++Qn)
#pragma unroll
            for (int n = 0; n < 2; ++n) {
              pv[Qn][n] = acc[Qm][Qn][m][n][r] * 0.125f;
              mx = fmaxf(mx, pv[Qn][n]);
            }
#pragma unroll
          for (int off = 1; off < 16; off <<= 1) mx = fmaxf(mx, __shfl_xor(mx, off));
          float s = 0.f;
#pragma unroll
          for (int Qn = 0; Qn < 2; ++Qn)
#pragma unroll
            for (int n = 0; n < 2; ++n) { pv[Qn][n] = __expf(pv[Qn][n] - mx); s += pv[Qn][n]; }
#pragma unroll
          for (int off = 1; off < 16; off <<= 1) s += __shfl_xor(s, off);
          float inv = 1.0f / s;
          long row = row0 + Qm * 128 + m * 16 + r;
#pragma unroll
          for (int Qn = 0; Qn < 2; ++Qn)
#pragma unroll
            for (int n = 0; n < 2; ++n)
              Cb[row * ldc + colw + Qn * 32 + n * 16 + lr] = f2bf(pv[Qn][n] * inv);
        }
  } else if (bn < 8) {
    // k: exp + per-batch column sums
    float cs[2][2] = {};
#pragma unroll
    for (int Qm = 0; Qm < 2; ++Qm)
#pragma unroll
      for (int m = 0; m < 4; ++m)
#pragma unroll
        for (int r = 0; r < 4; ++r) {
          long row = row0 + Qm * 128 + m * 16 + r;
#pragma unroll
          for (int Qn = 0; Qn < 2; ++Qn)
#pragma unroll
            for (int n = 0; n < 2; ++n) {
              float pe = __expf(acc[Qm][Qn][m][n][r]);
              cs[Qn][n] += pe;
              Cb[row * ldc + colw + Qn * 32 + n * 16 + lr] = f2bf(pe);
            }
        }
#pragma unroll
    for (int Qn = 0; Qn < 2; ++Qn)
#pragma unroll
      for (int n = 0; n < 2; ++n) {
        cs[Qn][n] += __shfl_xor(cs[Qn][n], 16);
        cs[Qn][n] += __shfl_xor(cs[Qn][n], 32);
      }
    if (lane < 16) {
      int b = bm >> 5;  // 32 row-tiles of 256 per batch
#pragma unroll
      for (int Qn = 0; Qn < 2; ++Qn)
#pragma unroll
        for (int n = 0; n < 2; ++n)
          atomicAdd(&S[b * DMODEL + (bn - 4) * 256 + wn * 64 + Qn * 32 + n * 16 + lane], cs[Qn][n]);
    }
  } else {
    // v: plain bf16 store
#pragma unroll
    for (int Qm = 0; Qm < 2; ++Qm)
#pragma unroll
      for (int m = 0; m < 4; ++m)
#pragma unroll
        for (int r = 0; r < 4; ++r) {
          long row = row0 + Qm * 128 + m * 16 + r;
#pragma unroll
          for (int Qn = 0; Qn < 2; ++Qn)
#pragma unroll
            for (int n = 0; n < 2; ++n)
              Cb[row * ldc + colw + Qn * 32 + n * 16 + lr] = f2bf(acc[Qm][Qn][m][n][r]);
        }
  }
}

// ---------------- context partial: ctx[bh][d][e] += sum_n q[n][d]*k[n][e] ----------------
__global__ __launch_bounds__(256) void k_ctx(const u16* __restrict__ qkv, float* __restrict__ ctx) {
  __shared__ float qs[64][64];
  __shared__ float ks[64][64];
  const int bh = blockIdx.x;
  const int b = bh >> 4, h = bh & 15;
  const int t = threadIdx.x;
  const int td = t & 15, te = t >> 4;
  float acc[4][4] = {};
  const long rowbase = (long)b * NSEQ + (long)blockIdx.y * 512;
  const u16* qbase = qkv + rowbase * QKVCOLS + h * 64;
  const u16* kbase = qkv + rowbase * QKVCOLS + DMODEL + h * 64;
  const int slr = t >> 2;
  const int slc = (t & 3) * 16;
  for (int st = 0; st < 8; ++st) {
    __syncthreads();
    const u16* qg = qbase + (long)(st * 64 + slr) * QKVCOLS + slc;
    const u16* kg = kbase + (long)(st * 64 + slr) * QKVCOLS + slc;
    short8 q0 = *(const short8*)qg, q1 = *(const short8*)(qg + 8);
    short8 kk0 = *(const short8*)kg, kk1 = *(const short8*)(kg + 8);
#pragma unroll
    for (int j = 0; j < 8; ++j) {
      qs[slr][slc + j] = bf2f((u16)q0[j]);
      qs[slr][slc + 8 + j] = bf2f((u16)q1[j]);
      ks[slr][slc + j] = bf2f((u16)kk0[j]);
      ks[slr][slc + 8 + j] = bf2f((u16)kk1[j]);
    }
    __syncthreads();
#pragma unroll 8
    for (int rr = 0; rr < 64; ++rr) {
      f32x4 qf = *(const f32x4*)&qs[rr][td * 4];
      f32x4 kf = *(const f32x4*)&ks[rr][te * 4];
#pragma unroll
      for (int i = 0; i < 4; ++i)
#pragma unroll
        for (int j = 0; j < 4; ++j)
          acc[i][j] += qf[i] * kf[j];
    }
  }
#pragma unroll
  for (int i = 0; i < 4; ++i)
#pragma unroll
    for (int j = 0; j < 4; ++j)
      atomicAdd(&ctx[((long)bh * 64 + td * 4 + i) * 64 + te * 4 + j], acc[i][j]);
}

// ---------------- normalize + transpose context ----------------
__global__ __launch_bounds__(256) void k_ctxnorm(const float* __restrict__ ctx,
                                                 const float* __restrict__ S,
                                                 u16* __restrict__ ctxT) {
  int bh = blockIdx.x;
  int b = bh >> 4, h = bh & 15;
  for (int i = threadIdx.x; i < 4096; i += 256) {
    int d = i >> 6, e = i & 63;
    float v = ctx[(long)bh * 4096 + i] / S[b * DMODEL + h * 64 + e];
    ctxT[(long)bh * 4096 + e * 64 + d] = f2bf(v);
  }
}

// ---------------- out_attn[n][h*64+e] = sum_d v[n][d] * ctx[d][e] ----------------
__global__ __launch_bounds__(256) void k_pv(const u16* __restrict__ qkv,
                                            const u16* __restrict__ ctxT,
                                            u16* __restrict__ oattn) {
  __shared__ __align__(16) u16 cs[64 * 64];
  const int bh = blockIdx.y;
  const int b = bh >> 4, h = bh & 15;
  const int t = threadIdx.x, lane = t & 63, w = t >> 6;
  {
    int i = t * 16;
    *(short8*)(cs + i) = *(const short8*)(ctxT + (long)bh * 4096 + i);
    *(short8*)(cs + i + 8) = *(const short8*)(ctxT + (long)bh * 4096 + i + 8);
  }
  __syncthreads();
  const long r0 = (long)blockIdx.x * 256 + w * 64;
  const u16* vbase = qkv + ((long)b * NSEQ + r0) * QKVCOLS + 2 * DMODEL + h * 64;
  f32x4 acc[4][4] = {};
  const int ko = (lane >> 4) * 8;
  const int lr = lane & 15;
#pragma unroll
  for (int ks = 0; ks < 2; ++ks) {
    bf16x8 af[4], bfr[4];
#pragma unroll
    for (int m = 0; m < 4; ++m)
      af[m] = *(const bf16x8*)(vbase + (long)(m * 16 + lr) * QKVCOLS + ks * 32 + ko);
#pragma unroll
    for (int n = 0; n < 4; ++n)
      bfr[n] = *(const bf16x8*)(cs + (n * 16 + lr) * 64 + ks * 32 + ko);
#pragma unroll
    for (int m = 0; m < 4; ++m)
#pragma unroll
      for (int n = 0; n < 4; ++n)
        acc[m][n] = __builtin_amdgcn_mfma_f32_16x16x32_bf16(af[m], bfr[n], acc[m][n], 0, 0, 0);
  }
#pragma unroll
  for (int m = 0; m < 4; ++m)
#pragma unroll
    for (int n = 0; n < 4; ++n)
#pragma unroll
      for (int r = 0; r < 4; ++r) {
        long row = r0 + m * 16 + (lane >> 4) * 4 + r;
        int col = h * 64 + n * 16 + lr;
        oattn[((long)b * NSEQ + row) * DMODEL + col] = f2bf(acc[m][n][r]);
      }
}

// ---------------- launch ----------------
extern "C" void kernel_launch(void* const* d_in, const int* in_sizes, int n_in,
                              void* d_out, int out_size, void* d_ws, size_t ws_size,
                              hipStream_t stream) {
  const float* x = (const float*)d_in[0];
  const float* w_qkv = (const float*)d_in[1];
  const float* w_out = (const float*)d_in[2];
  const float* b_out = (const float*)d_in[3];
  float* out = (float*)d_out;
  char* ws = (char*)d_ws;

  u16* xb     = (u16*)(ws + 0);                 // 64 MB
  u16* wqkvT  = (u16*)(ws + 67108864L);         // 6 MB
  u16* woutT  = (u16*)(ws + 73400320L);         // 2 MB
  u16* qkv    = (u16*)(ws + 75497472L);         // 192 MB
  u16* oattn  = (u16*)(ws + 276824064L);        // 64 MB
  float* S    = (float*)(ws + 343932928L);      // 16 KB
  float* ctx  = (float*)(ws + 343949312L);      // 1 MB
  u16* ctxT   = (u16*)(ws + 344997888L);        // 0.5 MB

  hipMemsetAsync(S, 0, 16384 + 1048576, stream);

  k_convert<<<32768, 256, 0, stream>>>(x, xb, (long)MROWS * DMODEL);
  k_transpose<<<dim3(96, 32), dim3(32, 8), 0, stream>>>(w_qkv, wqkvT, DMODEL, QKVCOLS);
  k_transpose<<<dim3(32, 32), dim3(32, 8), 0, stream>>>(w_out, woutT, DMODEL, DMODEL);

  // qkv GEMM (256x256 8-phase) with fused q-softmax / k-exp epilogue
  k_gemm256<0><<<dim3((MROWS / 256) * (QKVCOLS / 256)), 512, 0, stream>>>(
      xb, wqkvT, nullptr, qkv, nullptr, S, DMODEL, QKVCOLS / 256, QKVCOLS);

  k_ctx<<<dim3(64, 16), 256, 0, stream>>>(qkv, ctx);
  k_ctxnorm<<<64, 256, 0, stream>>>(ctx, S, ctxT);
  k_pv<<<dim3(32, 64), 256, 0, stream>>>(qkv, ctxT, oattn);

  // output GEMM (256x256 8-phase) fp32 + bias
  k_gemm256<1><<<dim3((MROWS / 256) * (DMODEL / 256)), 512, 0, stream>>>(
      oattn, woutT, b_out, nullptr, out, nullptr, DMODEL, DMODEL / 256, DMODEL);
}

// Round 4
// 454.301 us; speedup vs baseline: 1.4445x; 1.0108x over previous
//
#include <hip/hip_runtime.h>

typedef unsigned short u16;
typedef __attribute__((ext_vector_type(8))) short short8;
typedef __attribute__((ext_vector_type(4))) unsigned short u16x4;
typedef __attribute__((ext_vector_type(8))) __bf16 bf16x8;
typedef __attribute__((ext_vector_type(4))) float f32x4;

#define B_SZ 4
#define NSEQ 8192
#define DMODEL 1024
#define MROWS 32768
#define QKVCOLS 3072

static __device__ __forceinline__ u16 f2bf(float f) {
  unsigned u = __builtin_bit_cast(unsigned, f);
  u += 0x7fffu + ((u >> 16) & 1u);
  return (u16)(u >> 16);
}
static __device__ __forceinline__ float bf2f(u16 h) {
  return __builtin_bit_cast(float, ((unsigned)h) << 16);
}
static __device__ __forceinline__ void gload16(const u16* g, u16* l) {
  __builtin_amdgcn_global_load_lds(
      (const __attribute__((address_space(1))) unsigned*)g,
      (__attribute__((address_space(3))) unsigned*)l, 16, 0, 0);
}

// ---------------- fp32 -> bf16 convert ----------------
__global__ __launch_bounds__(256) void k_convert(const float* __restrict__ in,
                                                 u16* __restrict__ out, long n) {
  long i = ((long)blockIdx.x * 256 + threadIdx.x) * 4;
  if (i >= n) return;
  f32x4 v = *(const f32x4*)(in + i);
  u16x4 o;
  o[0] = f2bf(v[0]); o[1] = f2bf(v[1]); o[2] = f2bf(v[2]); o[3] = f2bf(v[3]);
  *(u16x4*)(out + i) = o;
}

// ---------------- transpose fp32[R][C] -> bf16[C][R] ----------------
__global__ __launch_bounds__(256) void k_transpose(const float* __restrict__ in,
                                                   u16* __restrict__ out, int R, int C) {
  __shared__ float tile[32][33];
  int c0 = blockIdx.x * 32, r0 = blockIdx.y * 32;
  int tx = threadIdx.x, ty = threadIdx.y;  // (32, 8)
#pragma unroll
  for (int j = 0; j < 32; j += 8)
    tile[ty + j][tx] = in[(long)(r0 + ty + j) * C + c0 + tx];
  __syncthreads();
#pragma unroll
  for (int j = 0; j < 32; j += 8)
    out[(long)(c0 + ty + j) * R + r0 + tx] = f2bf(tile[tx][ty + j]);
}

// ============ 256x256 8-phase bf16 GEMM: C = A[M][K] * B^T[N][K] ============
// EPI 0: qkv fused epilogue (bn<4 q-softmax, bn<8 k-exp+colsum, else v store)
// EPI 1: fp32 + bias
// A row stride = lda; B base += (bm>>5)*bstride (per-batch B, 0 = shared).
template <int EPI>
__global__ __launch_bounds__(512, 2) void k_gemm256(
    const u16* __restrict__ A, const u16* __restrict__ Bp,
    const float* __restrict__ bias, u16* __restrict__ Cb,
    float* __restrict__ Cf, float* __restrict__ S,
    int K, int lda, long bstride, int nbn, int ldc) {
  __shared__ __align__(16) u16 sm[65536];  // A0|A1|B0|B1, 16384 u16 each
  const int t = threadIdx.x;
  const int lane = t & 63;
  const int w = t >> 6;       // 0..7
  const int wq = w >> 2;      // row-half within quadrant
  const int wn = w & 3;       // col group
  const int lr = lane & 15;
  const int hi = lane >> 4;
  const int l3 = lane >> 3;

  // XCD swizzle + bm-group-of-8
  const int nwg = gridDim.x;
  const int bid = blockIdx.x;
  const int swz = (bid & 7) * (nwg >> 3) + (bid >> 3);
  const int per = 8 * nbn;
  const int grp = swz / per, rem = swz % per;
  const int bm = grp * 8 + (rem & 7);
  const int bn = rem / 8;

  const u16* B = Bp + (long)(bm >> 5) * bstride;
  const int gcol = ((lane & 7) ^ l3) * 8;  // swizzled k-offset (elements)

  auto stA = [&](int tile, int half, int buf) {
    u16* dst = &sm[buf * 16384 + (half * 128 + w * 16) * 64];
    const u16* g = A + ((long)(bm * 256 + half * 128 + w * 16 + l3)) * lda + tile * 64 + gcol;
    gload16(g, dst);
    gload16(g + 8 * (long)lda, dst + 8 * 64);
  };
  auto stB = [&](int tile, int half, int buf) {
#pragma unroll
    for (int L = 0; L < 2; ++L) {
      int base = half * 128 + w * 16 + L * 8;  // LDS B row base
      int grow = bn * 256 + ((base >> 5) & 3) * 64 + half * 32 + (base & 31) + l3;
      const u16* g = B + (long)grow * K + tile * 64 + gcol;
      gload16(g, &sm[32768 + buf * 16384 + base * 64]);
    }
  };

  const int su = (lr & 7) << 3;
  const int cu0 = (hi * 8) ^ su;         // kk=0 swizzled col (u16 units)
  const int cu1 = (32 + hi * 8) ^ su;    // kk=1
  const int arow = wq * 64 + lr;
  const int brow = wn * 32 + lr;

  auto ldA = [&](int buf, int Qm, int m, int kk) -> bf16x8 {
    return *(const bf16x8*)&sm[buf * 16384 + (Qm * 128 + arow + m * 16) * 64 + (kk ? cu1 : cu0)];
  };
  auto ldB = [&](int buf, int Qn, int n, int kk) -> bf16x8 {
    return *(const bf16x8*)&sm[32768 + buf * 16384 + (Qn * 128 + brow + n * 16) * 64 + (kk ? cu1 : cu0)];
  };

  f32x4 acc[2][2][4][2] = {};
  bf16x8 af[4][2], af2[4][2], bl[2][2], bh[2][2];
  const int NT = K >> 6;

  // prologue: tile0 full + Alo/Blo/Bhi of tile1; leave 3 half-tiles in flight
  stA(0, 0, 0); stB(0, 0, 0); stB(0, 1, 0); stA(0, 1, 0);
  stA(1, 0, 1); stB(1, 0, 1); stB(1, 1, 1);
  asm volatile("s_waitcnt vmcnt(6)" ::: "memory");
  __builtin_amdgcn_s_barrier();

  for (int tt = 0; tt < NT; ++tt) {
    const int p = tt & 1;
    const int c1 = (tt + 1 < NT) ? tt + 1 : NT - 1;
    const int c2 = (tt + 2 < NT) ? tt + 2 : NT - 1;
    // ---- P1: read af(Q0 A-lo) + bl; PREFETCH bh; MFMA quadrant (0,0) ----
#pragma unroll
    for (int m = 0; m < 4; ++m) { af[m][0] = ldA(p, 0, m, 0); af[m][1] = ldA(p, 0, m, 1); }
#pragma unroll
    for (int n = 0; n < 2; ++n) { bl[n][0] = ldB(p, 0, n, 0); bl[n][1] = ldB(p, 0, n, 1); }
#pragma unroll
    for (int n = 0; n < 2; ++n) { bh[n][0] = ldB(p, 1, n, 0); bh[n][1] = ldB(p, 1, n, 1); }
    stA(c1, 1, (tt + 1) & 1);
    __builtin_amdgcn_sched_barrier(0);
    __builtin_amdgcn_s_barrier();
    asm volatile("s_waitcnt lgkmcnt(4)" ::: "memory");  // af+bl done; bh in flight
    __builtin_amdgcn_sched_barrier(0);
    __builtin_amdgcn_s_setprio(1);
#pragma unroll
    for (int m = 0; m < 4; ++m)
#pragma unroll
      for (int n = 0; n < 2; ++n)
        acc[0][0][m][n] = __builtin_amdgcn_mfma_f32_16x16x32_bf16(af[m][1], bl[n][1],
            __builtin_amdgcn_mfma_f32_16x16x32_bf16(af[m][0], bl[n][0], acc[0][0][m][n], 0, 0, 0), 0, 0, 0);
    __builtin_amdgcn_s_setprio(0);
    __builtin_amdgcn_s_barrier();
    // ---- P2: PREFETCH af2 (A-hi); MFMA quadrant (0,1) ----
#pragma unroll
    for (int m = 0; m < 4; ++m) { af2[m][0] = ldA(p, 1, m, 0); af2[m][1] = ldA(p, 1, m, 1); }
    stA(c2, 0, p);
    __builtin_amdgcn_sched_barrier(0);
    __builtin_amdgcn_s_barrier();
    asm volatile("s_waitcnt lgkmcnt(8)" ::: "memory");  // bh done; af2 in flight
    __builtin_amdgcn_sched_barrier(0);
    __builtin_amdgcn_s_setprio(1);
#pragma unroll
    for (int m = 0; m < 4; ++m)
#pragma unroll
      for (int n = 0; n < 2; ++n)
        acc[0][1][m][n] = __builtin_amdgcn_mfma_f32_16x16x32_bf16(af[m][1], bh[n][1],
            __builtin_amdgcn_mfma_f32_16x16x32_bf16(af[m][0], bh[n][0], acc[0][1][m][n], 0, 0, 0), 0, 0, 0);
    __builtin_amdgcn_s_setprio(0);
    __builtin_amdgcn_s_barrier();
    // ---- P3: MFMA quadrant (1,1) with af2 ----
    stB(c2, 0, p);
    __builtin_amdgcn_sched_barrier(0);
    __builtin_amdgcn_s_barrier();
    asm volatile("s_waitcnt lgkmcnt(0)" ::: "memory");  // af2 done (covered by P2 MFMA)
    __builtin_amdgcn_sched_barrier(0);
    __builtin_amdgcn_s_setprio(1);
#pragma unroll
    for (int m = 0; m < 4; ++m)
#pragma unroll
      for (int n = 0; n < 2; ++n)
        acc[1][1][m][n] = __builtin_amdgcn_mfma_f32_16x16x32_bf16(af2[m][1], bh[n][1],
            __builtin_amdgcn_mfma_f32_16x16x32_bf16(af2[m][0], bh[n][0], acc[1][1][m][n], 0, 0, 0), 0, 0, 0);
    __builtin_amdgcn_s_setprio(0);
    __builtin_amdgcn_s_barrier();
    // ---- P4: MFMA quadrant (1,0) ----
    stB(c2, 1, p);
    __builtin_amdgcn_sched_barrier(0);
    __builtin_amdgcn_s_barrier();
    __builtin_amdgcn_s_setprio(1);
#pragma unroll
    for (int m = 0; m < 4; ++m)
#pragma unroll
      for (int n = 0; n < 2; ++n)
        acc[1][0][m][n] = __builtin_amdgcn_mfma_f32_16x16x32_bf16(af2[m][1], bl[n][1],
            __builtin_amdgcn_mfma_f32_16x16x32_bf16(af2[m][0], bl[n][0], acc[1][0][m][n], 0, 0, 0), 0, 0, 0);
    __builtin_amdgcn_s_setprio(0);
    asm volatile("s_waitcnt vmcnt(6)" ::: "memory");
    __builtin_amdgcn_s_barrier();
  }

  // ---------------- epilogue ----------------
  const int row0 = bm * 256 + wq * 64 + hi * 4;
  const int colw = bn * 256 + wn * 64;

  if (EPI == 1) {
#pragma unroll
    for (int Qm = 0; Qm < 2; ++Qm)
#pragma unroll
      for (int m = 0; m < 4; ++m)
#pragma unroll
        for (int r = 0; r < 4; ++r) {
          long row = row0 + Qm * 128 + m * 16 + r;
#pragma unroll
          for (int Qn = 0; Qn < 2; ++Qn)
#pragma unroll
            for (int n = 0; n < 2; ++n) {
              int col = colw + Qn * 32 + n * 16 + lr;
              Cf[row * ldc + col] = acc[Qm][Qn][m][n][r] + bias[col];
            }
        }
    return;
  }

  if (bn < 4) {
    // q: softmax over the wave's 64-col head segment, per row
#pragma unroll
    for (int Qm = 0; Qm < 2; ++Qm)
#pragma unroll
      for (int m = 0; m < 4; ++m)
#pragma unroll
        for (int r = 0; r < 4; ++r) {
          float pv[2][2];
          float mx = -1e30f;
#pragma unroll
          for (int Qn = 0; Qn < 2; ++Qn)
#pragma unroll
            for (int n = 0; n < 2; ++n) {
              pv[Qn][n] = acc[Qm][Qn][m][n][r] * 0.125f;
              mx = fmaxf(mx, pv[Qn][n]);
            }
#pragma unroll
          for (int off = 1; off < 16; off <<= 1) mx = fmaxf(mx, __shfl_xor(mx, off));
          float s = 0.f;
#pragma unroll
          for (int Qn = 0; Qn < 2; ++Qn)
#pragma unroll
            for (int n = 0; n < 2; ++n) { pv[Qn][n] = __expf(pv[Qn][n] - mx); s += pv[Qn][n]; }
#pragma unroll
          for (int off = 1; off < 16; off <<= 1) s += __shfl_xor(s, off);
          float inv = 1.0f / s;
          long row = row0 + Qm * 128 + m * 16 + r;
#pragma unroll
          for (int Qn = 0; Qn < 2; ++Qn)
#pragma unroll
            for (int n = 0; n < 2; ++n)
              Cb[row * ldc + colw + Qn * 32 + n * 16 + lr] = f2bf(pv[Qn][n] * inv);
        }
  } else if (bn < 8) {
    // k: exp + per-batch column sums
    float cs[2][2] = {};
#pragma unroll
    for (int Qm = 0; Qm < 2; ++Qm)
#pragma unroll
      for (int m = 0; m < 4; ++m)
#pragma unroll
        for (int r = 0; r < 4; ++r) {
          long row = row0 + Qm * 128 + m * 16 + r;
#pragma unroll
          for (int Qn = 0; Qn < 2; ++Qn)
#pragma unroll
            for (int n = 0; n < 2; ++n) {
              float pe = __expf(acc[Qm][Qn][m][n][r]);
              cs[Qn][n] += pe;
              Cb[row * ldc + colw + Qn * 32 + n * 16 + lr] = f2bf(pe);
            }
        }
#pragma unroll
    for (int Qn = 0; Qn < 2; ++Qn)
#pragma unroll
      for (int n = 0; n < 2; ++n) {
        cs[Qn][n] += __shfl_xor(cs[Qn][n], 16);
        cs[Qn][n] += __shfl_xor(cs[Qn][n], 32);
      }
    if (lane < 16) {
      int b = bm >> 5;  // 32 row-tiles of 256 per batch
#pragma unroll
      for (int Qn = 0; Qn < 2; ++Qn)
#pragma unroll
        for (int n = 0; n < 2; ++n)
          atomicAdd(&S[b * DMODEL + (bn - 4) * 256 + wn * 64 + Qn * 32 + n * 16 + lane], cs[Qn][n]);
    }
  } else {
    // v: plain bf16 store
#pragma unroll
    for (int Qm = 0; Qm < 2; ++Qm)
#pragma unroll
      for (int m = 0; m < 4; ++m)
#pragma unroll
        for (int r = 0; r < 4; ++r) {
          long row = row0 + Qm * 128 + m * 16 + r;
#pragma unroll
          for (int Qn = 0; Qn < 2; ++Qn)
#pragma unroll
            for (int n = 0; n < 2; ++n)
              Cb[row * ldc + colw + Qn * 32 + n * 16 + lr] = f2bf(acc[Qm][Qn][m][n][r]);
        }
  }
}

// ---------------- context partial: ctx[bh][d][e] += sum_n q[n][d]*k[n][e] ----------------
__global__ __launch_bounds__(256) void k_ctx(const u16* __restrict__ qkv, float* __restrict__ ctx) {
  __shared__ float qs[64][64];
  __shared__ float ks[64][64];
  const int bh = blockIdx.x;
  const int b = bh >> 4, h = bh & 15;
  const int t = threadIdx.x;
  const int td = t & 15, te = t >> 4;
  float acc[4][4] = {};
  const long rowbase = (long)b * NSEQ + (long)blockIdx.y * 512;
  const u16* qbase = qkv + rowbase * QKVCOLS + h * 64;
  const u16* kbase = qkv + rowbase * QKVCOLS + DMODEL + h * 64;
  const int slr = t >> 2;
  const int slc = (t & 3) * 16;
  for (int st = 0; st < 8; ++st) {
    __syncthreads();
    const u16* qg = qbase + (long)(st * 64 + slr) * QKVCOLS + slc;
    const u16* kg = kbase + (long)(st * 64 + slr) * QKVCOLS + slc;
    short8 q0 = *(const short8*)qg, q1 = *(const short8*)(qg + 8);
    short8 kk0 = *(const short8*)kg, kk1 = *(const short8*)(kg + 8);
#pragma unroll
    for (int j = 0; j < 8; ++j) {
      qs[slr][slc + j] = bf2f((u16)q0[j]);
      qs[slr][slc + 8 + j] = bf2f((u16)q1[j]);
      ks[slr][slc + j] = bf2f((u16)kk0[j]);
      ks[slr][slc + 8 + j] = bf2f((u16)kk1[j]);
    }
    __syncthreads();
#pragma unroll 8
    for (int rr = 0; rr < 64; ++rr) {
      f32x4 qf = *(const f32x4*)&qs[rr][td * 4];
      f32x4 kf = *(const f32x4*)&ks[rr][te * 4];
#pragma unroll
      for (int i = 0; i < 4; ++i)
#pragma unroll
        for (int j = 0; j < 4; ++j)
          acc[i][j] += qf[i] * kf[j];
    }
  }
#pragma unroll
  for (int i = 0; i < 4; ++i)
#pragma unroll
    for (int j = 0; j < 4; ++j)
      atomicAdd(&ctx[((long)bh * 64 + td * 4 + i) * 64 + te * 4 + j], acc[i][j]);
}

// ---------------- W2[b][eo][hd] = sum_e ctxn[b,h][d][e] * woutT[eo][h*64+e] ----------------
// grid (4, 16, 8), 256 threads. W2 stored as B^T layout [eo][hd] per batch (bf16).
__global__ __launch_bounds__(256) void k_w2(const float* __restrict__ ctx,
                                            const float* __restrict__ S,
                                            const u16* __restrict__ woutT,
                                            u16* __restrict__ w2t) {
  __shared__ float cl[64][68];
  const int b = blockIdx.x, h = blockIdx.y, ec = blockIdx.z;
  const float* cp = ctx + ((long)(b * 16 + h)) * 4096;
  const float* Sp = S + b * DMODEL + h * 64;
  for (int i = threadIdx.x; i < 4096; i += 256) {
    int d = i >> 6, e = i & 63;
    cl[d][e] = cp[i] / Sp[e];
  }
  __syncthreads();
  const int eo = ec * 128 + (threadIdx.x & 127);
  const int dg = (threadIdx.x >> 7) * 32;
  const u16* wp = woutT + (long)eo * DMODEL + h * 64;
  f32x4 w4[16];
#pragma unroll
  for (int j = 0; j < 16; ++j) {
    short8 wv = *(const short8*)(wp + j * 4);  // only first 4 used? load 4 bf16
    (void)wv;
  }
  // load 64 bf16 weights
  float w[64];
#pragma unroll
  for (int j = 0; j < 8; ++j) {
    short8 wv = *(const short8*)(wp + j * 8);
#pragma unroll
    for (int i = 0; i < 8; ++i) w[j * 8 + i] = bf2f((u16)wv[i]);
  }
#pragma unroll
  for (int j = 0; j < 16; ++j) w4[j] = *(const f32x4*)&w[j * 4];
  u16* outp = w2t + ((long)b << 20) + (long)eo * DMODEL + h * 64;
  for (int d = dg; d < dg + 32; ++d) {
    f32x4 a = {0.f, 0.f, 0.f, 0.f};
#pragma unroll
    for (int j = 0; j < 16; ++j) {
      f32x4 c4 = *(const f32x4*)&cl[d][j * 4];
      a += c4 * w4[j];
    }
    outp[d] = f2bf(a[0] + a[1] + a[2] + a[3]);
  }
}

// ---------------- launch ----------------
extern "C" void kernel_launch(void* const* d_in, const int* in_sizes, int n_in,
                              void* d_out, int out_size, void* d_ws, size_t ws_size,
                              hipStream_t stream) {
  const float* x = (const float*)d_in[0];
  const float* w_qkv = (const float*)d_in[1];
  const float* w_out = (const float*)d_in[2];
  const float* b_out = (const float*)d_in[3];
  float* out = (float*)d_out;
  char* ws = (char*)d_ws;

  u16* xb     = (u16*)(ws + 0);                 // 64 MB
  u16* wqkvT  = (u16*)(ws + 67108864L);         // 6 MB
  u16* woutT  = (u16*)(ws + 73400320L);         // 2 MB
  u16* qkv    = (u16*)(ws + 75497472L);         // 192 MB
  u16* w2t    = (u16*)(ws + 276824064L);        // 8 MB
  float* S    = (float*)(ws + 285212672L);      // 16 KB
  float* ctx  = (float*)(ws + 285229056L);      // 1 MB

  hipMemsetAsync(S, 0, 16384 + 1048576, stream);

  k_convert<<<32768, 256, 0, stream>>>(x, xb, (long)MROWS * DMODEL);
  k_transpose<<<dim3(96, 32), dim3(32, 8), 0, stream>>>(w_qkv, wqkvT, DMODEL, QKVCOLS);
  k_transpose<<<dim3(32, 32), dim3(32, 8), 0, stream>>>(w_out, woutT, DMODEL, DMODEL);

  // qkv GEMM (256x256, prefetch-pipelined) with fused q-softmax / k-exp epilogue
  k_gemm256<0><<<dim3((MROWS / 256) * (QKVCOLS / 256)), 512, 0, stream>>>(
      xb, wqkvT, nullptr, qkv, nullptr, S, DMODEL, DMODEL, 0L, QKVCOLS / 256, QKVCOLS);

  k_ctx<<<dim3(64, 16), 256, 0, stream>>>(qkv, ctx);
  k_w2<<<dim3(4, 16, 8), 256, 0, stream>>>(ctx, S, woutT, w2t);

  // out GEMM: out = v (in qkv, lda=3072) x W2[b]^T + bias, fp32 store
  k_gemm256<1><<<dim3((MROWS / 256) * (DMODEL / 256)), 512, 0, stream>>>(
      qkv + 2 * DMODEL, w2t, b_out, nullptr, out, nullptr,
      DMODEL, QKVCOLS, (long)DMODEL * DMODEL, DMODEL / 256, DMODEL);
}

// Round 5
// 445.777 us; speedup vs baseline: 1.4721x; 1.0191x over previous
//
#include <hip/hip_runtime.h>

typedef unsigned short u16;
typedef __attribute__((ext_vector_type(8))) short short8;
typedef __attribute__((ext_vector_type(4))) unsigned short u16x4;
typedef __attribute__((ext_vector_type(8))) __bf16 bf16x8;
typedef __attribute__((ext_vector_type(4))) float f32x4;

#define B_SZ 4
#define NSEQ 8192
#define DMODEL 1024
#define MROWS 32768
#define QKVCOLS 3072

static __device__ __forceinline__ u16 f2bf(float f) {
  unsigned u = __builtin_bit_cast(unsigned, f);
  u += 0x7fffu + ((u >> 16) & 1u);
  return (u16)(u >> 16);
}
static __device__ __forceinline__ float bf2f(u16 h) {
  return __builtin_bit_cast(float, ((unsigned)h) << 16);
}
static __device__ __forceinline__ void gload16(const u16* g, u16* l) {
  __builtin_amdgcn_global_load_lds(
      (const __attribute__((address_space(1))) unsigned*)g,
      (__attribute__((address_space(3))) unsigned*)l, 16, 0, 0);
}

// ---------------- fp32 -> bf16 convert ----------------
__global__ __launch_bounds__(256) void k_convert(const float* __restrict__ in,
                                                 u16* __restrict__ out, long n) {
  long i = ((long)blockIdx.x * 256 + threadIdx.x) * 4;
  if (i >= n) return;
  f32x4 v = *(const f32x4*)(in + i);
  u16x4 o;
  o[0] = f2bf(v[0]); o[1] = f2bf(v[1]); o[2] = f2bf(v[2]); o[3] = f2bf(v[3]);
  *(u16x4*)(out + i) = o;
}

// ---------------- transpose fp32[R][C] -> bf16[C][R] ----------------
__global__ __launch_bounds__(256) void k_transpose(const float* __restrict__ in,
                                                   u16* __restrict__ out, int R, int C) {
  __shared__ float tile[32][33];
  int c0 = blockIdx.x * 32, r0 = blockIdx.y * 32;
  int tx = threadIdx.x, ty = threadIdx.y;  // (32, 8)
#pragma unroll
  for (int j = 0; j < 32; j += 8)
    tile[ty + j][tx] = in[(long)(r0 + ty + j) * C + c0 + tx];
  __syncthreads();
#pragma unroll
  for (int j = 0; j < 32; j += 8)
    out[(long)(c0 + ty + j) * R + r0 + tx] = f2bf(tile[tx][ty + j]);
}

// ============ 256x256 3-phase bf16 GEMM: C = A[M][K] * B^T[N][K] ============
// EPI 0: qkv fused epilogue (bn<4 q-softmax, bn<8 k-exp+colsum, else v store)
// EPI 1: fp32 + bias
#define MFMA_QUAD(Qm, Qn, A_, B_)                                              \
  _Pragma("unroll") for (int m = 0; m < 4; ++m)                                \
  _Pragma("unroll") for (int n = 0; n < 2; ++n)                                \
    acc[Qm][Qn][m][n] = __builtin_amdgcn_mfma_f32_16x16x32_bf16(A_[m][1], B_[n][1], \
        __builtin_amdgcn_mfma_f32_16x16x32_bf16(A_[m][0], B_[n][0], acc[Qm][Qn][m][n], 0, 0, 0), 0, 0, 0);

template <int EPI, int K, int LDA, int NBN, int LDC, long BSTR>
__global__ __launch_bounds__(512, 2) void k_gemm256(
    const u16* __restrict__ A, const u16* __restrict__ Bp,
    const float* __restrict__ bias, u16* __restrict__ Cb,
    float* __restrict__ Cf, float* __restrict__ S) {
  __shared__ __align__(16) u16 sm[65536];  // A0|A1|B0|B1, 16384 u16 each
  const int t = threadIdx.x;
  const int lane = t & 63;
  const int w = t >> 6;       // 0..7
  const int wq = w >> 2;      // row-half within quadrant
  const int wn = w & 3;       // col group
  const int lr = lane & 15;
  const int hi = lane >> 4;
  const int l3 = lane >> 3;

  // XCD swizzle + bm-group-of-8
  const int nwg = gridDim.x;
  const int bid = blockIdx.x;
  const int swz = (bid & 7) * (nwg >> 3) + (bid >> 3);
  const int per = 8 * NBN;
  const int grp = swz / per, rem = swz % per;
  const int bm = grp * 8 + (rem & 7);
  const int bn = rem / 8;

  const u16* B = Bp + (long)(bm >> 5) * BSTR;
  const int gcol = ((lane & 7) ^ l3) * 8;  // swizzled k-offset (elements)

  auto stA = [&](int tile, int half, int buf) {
    u16* dst = &sm[buf * 16384 + (half * 128 + w * 16) * 64];
    const u16* g = A + ((long)(bm * 256 + half * 128 + w * 16 + l3)) * LDA + tile * 64 + gcol;
    gload16(g, dst);
    gload16(g + 8 * (long)LDA, dst + 8 * 64);
  };
  auto stB = [&](int tile, int half, int buf) {
#pragma unroll
    for (int L = 0; L < 2; ++L) {
      int base = half * 128 + w * 16 + L * 8;  // LDS B row base
      int grow = bn * 256 + ((base >> 5) & 3) * 64 + half * 32 + (base & 31) + l3;
      const u16* g = B + (long)grow * K + tile * 64 + gcol;
      gload16(g, &sm[32768 + buf * 16384 + base * 64]);
    }
  };

  const int su = (lr & 7) << 3;
  const int cu0 = (hi * 8) ^ su;         // kk=0 swizzled col (u16 units)
  const int cu1 = (32 + hi * 8) ^ su;    // kk=1
  const int arow = wq * 64 + lr;
  const int brow = wn * 32 + lr;

  auto ldA = [&](int buf, int Qm, int m, int kk) -> bf16x8 {
    return *(const bf16x8*)&sm[buf * 16384 + (Qm * 128 + arow + m * 16) * 64 + (kk ? cu1 : cu0)];
  };
  auto ldB = [&](int buf, int Qn, int n, int kk) -> bf16x8 {
    return *(const bf16x8*)&sm[32768 + buf * 16384 + (Qn * 128 + brow + n * 16) * 64 + (kk ? cu1 : cu0)];
  };

  f32x4 acc[2][2][4][2] = {};
  bf16x8 af[4][2], af2[4][2], bl[2][2], bh[2][2];
  constexpr int NT = K >> 6;

  // prologue: tile0 full + Alo/Blo/Bhi of tile1; 14 gloads, need first 8 done
  stA(0, 0, 0); stB(0, 0, 0); stB(0, 1, 0); stA(0, 1, 0);
  stA(1, 0, 1); stB(1, 0, 1); stB(1, 1, 1);
  asm volatile("s_waitcnt vmcnt(6)" ::: "memory");
  __builtin_amdgcn_s_barrier();

  auto tile_body = [&](int tt, int s1, int s2) {
    const int p = tt & 1;
    // ---- P1: read af + bl, then bh (prefetch); stage A(tt+1,h1); MFMA Q00 --
#pragma unroll
    for (int m = 0; m < 4; ++m) { af[m][0] = ldA(p, 0, m, 0); af[m][1] = ldA(p, 0, m, 1); }
#pragma unroll
    for (int n = 0; n < 2; ++n) { bl[n][0] = ldB(p, 0, n, 0); bl[n][1] = ldB(p, 0, n, 1); }
    __builtin_amdgcn_sched_barrier(0);
#pragma unroll
    for (int n = 0; n < 2; ++n) { bh[n][0] = ldB(p, 1, n, 0); bh[n][1] = ldB(p, 1, n, 1); }
    __builtin_amdgcn_sched_barrier(0);
    if (s1) stA(tt + 1, 1, 1 - p);
    __builtin_amdgcn_sched_barrier(0);
    asm volatile("s_waitcnt lgkmcnt(4)" ::: "memory");   // af+bl done; bh in flight
    __builtin_amdgcn_sched_barrier(0);
    __builtin_amdgcn_s_setprio(1);
    MFMA_QUAD(0, 0, af, bl)
    __builtin_amdgcn_s_setprio(0);
    __builtin_amdgcn_s_barrier();
    // ---- P2: read af2 (prefetch); stage A(tt+2,h0); MFMA Q01 ----
#pragma unroll
    for (int m = 0; m < 4; ++m) { af2[m][0] = ldA(p, 1, m, 0); af2[m][1] = ldA(p, 1, m, 1); }
    __builtin_amdgcn_sched_barrier(0);
    if (s2) stA(tt + 2, 0, p);
    __builtin_amdgcn_sched_barrier(0);
    asm volatile("s_waitcnt lgkmcnt(8)" ::: "memory");   // bh done; af2 in flight
    __builtin_amdgcn_sched_barrier(0);
    __builtin_amdgcn_s_setprio(1);
    MFMA_QUAD(0, 1, af, bh)
    __builtin_amdgcn_s_setprio(0);
    __builtin_amdgcn_s_barrier();
    // ---- P3: stage B(tt+2); MFMA Q11 + Q10 (32 MFMAs, regs only) ----
    if (s2) { stB(tt + 2, 0, p); stB(tt + 2, 1, p); }
    __builtin_amdgcn_sched_barrier(0);
    asm volatile("s_waitcnt lgkmcnt(0)" ::: "memory");   // af2 done
    __builtin_amdgcn_sched_barrier(0);
    __builtin_amdgcn_s_setprio(1);
    MFMA_QUAD(1, 1, af2, bh)
    MFMA_QUAD(1, 0, af2, bl)
    __builtin_amdgcn_s_setprio(0);
    if (s2) { asm volatile("s_waitcnt vmcnt(6)" ::: "memory"); }
    else if (s1) { asm volatile("s_waitcnt vmcnt(0)" ::: "memory"); }
    __builtin_amdgcn_s_barrier();
  };

  for (int tt = 0; tt < NT - 2; ++tt) tile_body(tt, 1, 1);
  tile_body(NT - 2, 1, 0);
  tile_body(NT - 1, 0, 0);

  // ---------------- epilogue ----------------
  const int row0 = bm * 256 + wq * 64 + hi * 4;
  const int colw = bn * 256 + wn * 64;

  if (EPI == 1) {
#pragma unroll
    for (int Qm = 0; Qm < 2; ++Qm)
#pragma unroll
      for (int m = 0; m < 4; ++m)
#pragma unroll
        for (int r = 0; r < 4; ++r) {
          long row = row0 + Qm * 128 + m * 16 + r;
#pragma unroll
          for (int Qn = 0; Qn < 2; ++Qn)
#pragma unroll
            for (int n = 0; n < 2; ++n) {
              int col = colw + Qn * 32 + n * 16 + lr;
              Cf[row * LDC + col] = acc[Qm][Qn][m][n][r] + bias[col];
            }
        }
    return;
  }

  if (bn < 4) {
    // q: softmax over the wave's 64-col head segment, per row
#pragma unroll
    for (int Qm = 0; Qm < 2; ++Qm)
#pragma unroll
      for (int m = 0; m < 4; ++m)
#pragma unroll
        for (int r = 0; r < 4; ++r) {
          float pv[2][2];
          float mx = -1e30f;
#pragma unroll
          for (int Qn = 0; Qn < 2; ++Qn)
#pragma unroll
            for (int n = 0; n < 2; ++n) {
              pv[Qn][n] = acc[Qm][Qn][m][n][r] * 0.125f;
              mx = fmaxf(mx, pv[Qn][n]);
            }
#pragma unroll
          for (int off = 1; off < 16; off <<= 1) mx = fmaxf(mx, __shfl_xor(mx, off));
          float s = 0.f;
#pragma unroll
          for (int Qn = 0; Qn < 2; ++Qn)
#pragma unroll
            for (int n = 0; n < 2; ++n) { pv[Qn][n] = __expf(pv[Qn][n] - mx); s += pv[Qn][n]; }
#pragma unroll
          for (int off = 1; off < 16; off <<= 1) s += __shfl_xor(s, off);
          float inv = 1.0f / s;
          long row = row0 + Qm * 128 + m * 16 + r;
#pragma unroll
          for (int Qn = 0; Qn < 2; ++Qn)
#pragma unroll
            for (int n = 0; n < 2; ++n)
              Cb[row * LDC + colw + Qn * 32 + n * 16 + lr] = f2bf(pv[Qn][n] * inv);
        }
  } else if (bn < 8) {
    // k: exp + per-batch column sums
    float cs[2][2] = {};
#pragma unroll
    for (int Qm = 0; Qm < 2; ++Qm)
#pragma unroll
      for (int m = 0; m < 4; ++m)
#pragma unroll
        for (int r = 0; r < 4; ++r) {
          long row = row0 + Qm * 128 + m * 16 + r;
#pragma unroll
          for (int Qn = 0; Qn < 2; ++Qn)
#pragma unroll
            for (int n = 0; n < 2; ++n) {
              float pe = __expf(acc[Qm][Qn][m][n][r]);
              cs[Qn][n] += pe;
              Cb[row * LDC + colw + Qn * 32 + n * 16 + lr] = f2bf(pe);
            }
        }
#pragma unroll
    for (int Qn = 0; Qn < 2; ++Qn)
#pragma unroll
      for (int n = 0; n < 2; ++n) {
        cs[Qn][n] += __shfl_xor(cs[Qn][n], 16);
        cs[Qn][n] += __shfl_xor(cs[Qn][n], 32);
      }
    if (lane < 16) {
      int b = bm >> 5;  // 32 row-tiles of 256 per batch
#pragma unroll
      for (int Qn = 0; Qn < 2; ++Qn)
#pragma unroll
        for (int n = 0; n < 2; ++n)
          atomicAdd(&S[b * DMODEL + (bn - 4) * 256 + wn * 64 + Qn * 32 + n * 16 + lane], cs[Qn][n]);
    }
  } else {
    // v: plain bf16 store
#pragma unroll
    for (int Qm = 0; Qm < 2; ++Qm)
#pragma unroll
      for (int m = 0; m < 4; ++m)
#pragma unroll
        for (int r = 0; r < 4; ++r) {
          long row = row0 + Qm * 128 + m * 16 + r;
#pragma unroll
          for (int Qn = 0; Qn < 2; ++Qn)
#pragma unroll
            for (int n = 0; n < 2; ++n)
              Cb[row * LDC + colw + Qn * 32 + n * 16 + lr] = f2bf(acc[Qm][Qn][m][n][r]);
        }
  }
}

// ---------------- context partial: ctx[bh][d][e] += sum_n q[n][d]*k[n][e] ----------------
__global__ __launch_bounds__(256) void k_ctx(const u16* __restrict__ qkv, float* __restrict__ ctx) {
  __shared__ float qs[64][64];
  __shared__ float ks[64][64];
  const int bh = blockIdx.x;
  const int b = bh >> 4, h = bh & 15;
  const int t = threadIdx.x;
  const int td = t & 15, te = t >> 4;
  float acc[4][4] = {};
  const long rowbase = (long)b * NSEQ + (long)blockIdx.y * 512;
  const u16* qbase = qkv + rowbase * QKVCOLS + h * 64;
  const u16* kbase = qkv + rowbase * QKVCOLS + DMODEL + h * 64;
  const int slr = t >> 2;
  const int slc = (t & 3) * 16;
  for (int st = 0; st < 8; ++st) {
    __syncthreads();
    const u16* qg = qbase + (long)(st * 64 + slr) * QKVCOLS + slc;
    const u16* kg = kbase + (long)(st * 64 + slr) * QKVCOLS + slc;
    short8 q0 = *(const short8*)qg, q1 = *(const short8*)(qg + 8);
    short8 kk0 = *(const short8*)kg, kk1 = *(const short8*)(kg + 8);
#pragma unroll
    for (int j = 0; j < 8; ++j) {
      qs[slr][slc + j] = bf2f((u16)q0[j]);
      qs[slr][slc + 8 + j] = bf2f((u16)q1[j]);
      ks[slr][slc + j] = bf2f((u16)kk0[j]);
      ks[slr][slc + 8 + j] = bf2f((u16)kk1[j]);
    }
    __syncthreads();
#pragma unroll 8
    for (int rr = 0; rr < 64; ++rr) {
      f32x4 qf = *(const f32x4*)&qs[rr][td * 4];
      f32x4 kf = *(const f32x4*)&ks[rr][te * 4];
#pragma unroll
      for (int i = 0; i < 4; ++i)
#pragma unroll
        for (int j = 0; j < 4; ++j)
          acc[i][j] += qf[i] * kf[j];
    }
  }
#pragma unroll
  for (int i = 0; i < 4; ++i)
#pragma unroll
    for (int j = 0; j < 4; ++j)
      atomicAdd(&ctx[((long)bh * 64 + td * 4 + i) * 64 + te * 4 + j], acc[i][j]);
}

// ---------------- W2[b][eo][hd] = sum_e ctxn[b,h][d][e] * woutT[eo][h*64+e] ----------------
// grid (4, 16, 8), 256 threads. W2 stored as B^T layout [eo][hd] per batch (bf16).
__global__ __launch_bounds__(256) void k_w2(const float* __restrict__ ctx,
                                            const float* __restrict__ S,
                                            const u16* __restrict__ woutT,
                                            u16* __restrict__ w2t) {
  __shared__ float cl[64][68];
  const int b = blockIdx.x, h = blockIdx.y, ec = blockIdx.z;
  const float* cp = ctx + ((long)(b * 16 + h)) * 4096;
  const float* Sp = S + b * DMODEL + h * 64;
  for (int i = threadIdx.x; i < 4096; i += 256) {
    int d = i >> 6, e = i & 63;
    cl[d][e] = cp[i] / Sp[e];
  }
  __syncthreads();
  const int eo = ec * 128 + (threadIdx.x & 127);
  const int dg = (threadIdx.x >> 7) * 32;
  const u16* wp = woutT + (long)eo * DMODEL + h * 64;
  float wv[64];
#pragma unroll
  for (int j = 0; j < 8; ++j) {
    short8 v8 = *(const short8*)(wp + j * 8);
#pragma unroll
    for (int i = 0; i < 8; ++i) wv[j * 8 + i] = bf2f((u16)v8[i]);
  }
  f32x4 w4[16];
#pragma unroll
  for (int j = 0; j < 16; ++j) w4[j] = *(const f32x4*)&wv[j * 4];
  u16* outp = w2t + ((long)b << 20) + (long)eo * DMODEL + h * 64;
  for (int d = dg; d < dg + 32; ++d) {
    f32x4 a = {0.f, 0.f, 0.f, 0.f};
#pragma unroll
    for (int j = 0; j < 16; ++j) {
      f32x4 c4 = *(const f32x4*)&cl[d][j * 4];
      a += c4 * w4[j];
    }
    outp[d] = f2bf(a[0] + a[1] + a[2] + a[3]);
  }
}

// ---------------- launch ----------------
extern "C" void kernel_launch(void* const* d_in, const int* in_sizes, int n_in,
                              void* d_out, int out_size, void* d_ws, size_t ws_size,
                              hipStream_t stream) {
  const float* x = (const float*)d_in[0];
  const float* w_qkv = (const float*)d_in[1];
  const float* w_out = (const float*)d_in[2];
  const float* b_out = (const float*)d_in[3];
  float* out = (float*)d_out;
  char* ws = (char*)d_ws;

  u16* xb     = (u16*)(ws + 0);                 // 64 MB
  u16* wqkvT  = (u16*)(ws + 67108864L);         // 6 MB
  u16* woutT  = (u16*)(ws + 73400320L);         // 2 MB
  u16* qkv    = (u16*)(ws + 75497472L);         // 192 MB
  u16* w2t    = (u16*)(ws + 276824064L);        // 8 MB
  float* S    = (float*)(ws + 285212672L);      // 16 KB
  float* ctx  = (float*)(ws + 285229056L);      // 1 MB

  hipMemsetAsync(S, 0, 16384 + 1048576, stream);

  k_convert<<<32768, 256, 0, stream>>>(x, xb, (long)MROWS * DMODEL);
  k_transpose<<<dim3(96, 32), dim3(32, 8), 0, stream>>>(w_qkv, wqkvT, DMODEL, QKVCOLS);
  k_transpose<<<dim3(32, 32), dim3(32, 8), 0, stream>>>(w_out, woutT, DMODEL, DMODEL);

  // qkv GEMM (256x256, 3-phase) with fused q-softmax / k-exp epilogue
  k_gemm256<0, DMODEL, DMODEL, 12, QKVCOLS, 0L>
      <<<dim3((MROWS / 256) * (QKVCOLS / 256)), 512, 0, stream>>>(
      xb, wqkvT, nullptr, qkv, nullptr, S);

  k_ctx<<<dim3(64, 16), 256, 0, stream>>>(qkv, ctx);
  k_w2<<<dim3(4, 16, 8), 256, 0, stream>>>(ctx, S, woutT, w2t);

  // out GEMM: out = v (in qkv, lda=3072) x W2[b]^T + bias, fp32 store
  k_gemm256<1, DMODEL, QKVCOLS, 4, DMODEL, (long)DMODEL * DMODEL>
      <<<dim3((MROWS / 256) * (DMODEL / 256)), 512, 0, stream>>>(
      qkv + 2 * DMODEL, w2t, b_out, nullptr, out, nullptr);
}

// Round 7
// 390.111 us; speedup vs baseline: 1.6822x; 1.1427x over previous
//
#include <hip/hip_runtime.h>

typedef unsigned short u16;
typedef __attribute__((ext_vector_type(8))) short short8;
typedef __attribute__((ext_vector_type(4))) unsigned short u16x4;
typedef __attribute__((ext_vector_type(8))) __bf16 bf16x8;
typedef __attribute__((ext_vector_type(4))) float f32x4;

#define B_SZ 4
#define NSEQ 8192
#define DMODEL 1024
#define MROWS 32768
#define QKVCOLS 3072

static __device__ __forceinline__ u16 f2bf(float f) {
  unsigned u = __builtin_bit_cast(unsigned, f);
  u += 0x7fffu + ((u >> 16) & 1u);
  return (u16)(u >> 16);
}
static __device__ __forceinline__ float bf2f(u16 h) {
  return __builtin_bit_cast(float, ((unsigned)h) << 16);
}
static __device__ __forceinline__ void gload16(const u16* g, u16* l) {
  __builtin_amdgcn_global_load_lds(
      (const __attribute__((address_space(1))) unsigned*)g,
      (__attribute__((address_space(3))) unsigned*)l, 16, 0, 0);
}

// ---------------- fp32 -> bf16 convert ----------------
__global__ __launch_bounds__(256) void k_convert(const float* __restrict__ in,
                                                 u16* __restrict__ out, long n) {
  long i = ((long)blockIdx.x * 256 + threadIdx.x) * 4;
  if (i >= n) return;
  f32x4 v = *(const f32x4*)(in + i);
  u16x4 o;
  o[0] = f2bf(v[0]); o[1] = f2bf(v[1]); o[2] = f2bf(v[2]); o[3] = f2bf(v[3]);
  *(u16x4*)(out + i) = o;
}

// ---------------- transpose fp32[R][C] -> bf16[C][R] ----------------
__global__ __launch_bounds__(256) void k_transpose(const float* __restrict__ in,
                                                   u16* __restrict__ out, int R, int C) {
  __shared__ float tile[32][33];
  int c0 = blockIdx.x * 32, r0 = blockIdx.y * 32;
  int tx = threadIdx.x, ty = threadIdx.y;  // (32, 8)
#pragma unroll
  for (int j = 0; j < 32; j += 8)
    tile[ty + j][tx] = in[(long)(r0 + ty + j) * C + c0 + tx];
  __syncthreads();
#pragma unroll
  for (int j = 0; j < 32; j += 8)
    out[(long)(c0 + ty + j) * R + r0 + tx] = f2bf(tile[tx][ty + j]);
}

// ============ 256x256 3-phase bf16 GEMM: C = A[M][K] * B^T[N][K] ============
// EPI 0: qkv fused epilogue -> qhat/khat head-major [bh][n][64] (+softmax/exp+colsum), vhat [n][1024]
// EPI 1: fp32 + bias to Cf
#define MFMA_QUAD(Qm, Qn, A_, B_)                                              \
  _Pragma("unroll") for (int m = 0; m < 4; ++m)                                \
  _Pragma("unroll") for (int n = 0; n < 2; ++n)                                \
    acc[Qm][Qn][m][n] = __builtin_amdgcn_mfma_f32_16x16x32_bf16(A_[m][1], B_[n][1], \
        __builtin_amdgcn_mfma_f32_16x16x32_bf16(A_[m][0], B_[n][0], acc[Qm][Qn][m][n], 0, 0, 0), 0, 0, 0);

template <int EPI, int K, int LDA, int NBN, int LDC, long BSTR>
__global__ __launch_bounds__(512, 2) void k_gemm256(
    const u16* __restrict__ A, const u16* __restrict__ Bp,
    const float* __restrict__ bias, u16* __restrict__ qh,
    u16* __restrict__ kh, u16* __restrict__ vh,
    float* __restrict__ Cf, float* __restrict__ S) {
  __shared__ __align__(16) u16 sm[65536];  // A0|A1|B0|B1, 16384 u16 each
  const int t = threadIdx.x;
  const int lane = t & 63;
  const int w = t >> 6;       // 0..7
  const int wq = w >> 2;      // row-half within quadrant
  const int wn = w & 3;       // col group
  const int lr = lane & 15;
  const int hi = lane >> 4;
  const int l3 = lane >> 3;

  // XCD swizzle + bm-group-of-8
  const int nwg = gridDim.x;
  const int bid = blockIdx.x;
  const int swz = (bid & 7) * (nwg >> 3) + (bid >> 3);
  const int per = 8 * NBN;
  const int grp = swz / per, rem = swz % per;
  const int bm = grp * 8 + (rem & 7);
  const int bn = rem / 8;

  const u16* B = Bp + (long)(bm >> 5) * BSTR;
  const int gcol = ((lane & 7) ^ l3) * 8;  // swizzled k-offset (elements)

  auto stA = [&](int tile, int half, int buf) {
    u16* dst = &sm[buf * 16384 + (half * 128 + w * 16) * 64];
    const u16* g = A + ((long)(bm * 256 + half * 128 + w * 16 + l3)) * LDA + tile * 64 + gcol;
    gload16(g, dst);
    gload16(g + 8 * (long)LDA, dst + 8 * 64);
  };
  auto stB = [&](int tile, int half, int buf) {
#pragma unroll
    for (int L = 0; L < 2; ++L) {
      int base = half * 128 + w * 16 + L * 8;  // LDS B row base
      int grow = bn * 256 + ((base >> 5) & 3) * 64 + half * 32 + (base & 31) + l3;
      const u16* g = B + (long)grow * K + tile * 64 + gcol;
      gload16(g, &sm[32768 + buf * 16384 + base * 64]);
    }
  };

  const int su = (lr & 7) << 3;
  const int cu0 = (hi * 8) ^ su;         // kk=0 swizzled col (u16 units)
  const int cu1 = (32 + hi * 8) ^ su;    // kk=1
  const int arow = wq * 64 + lr;
  const int brow = wn * 32 + lr;

  auto ldA = [&](int buf, int Qm, int m, int kk) -> bf16x8 {
    return *(const bf16x8*)&sm[buf * 16384 + (Qm * 128 + arow + m * 16) * 64 + (kk ? cu1 : cu0)];
  };
  auto ldB = [&](int buf, int Qn, int n, int kk) -> bf16x8 {
    return *(const bf16x8*)&sm[32768 + buf * 16384 + (Qn * 128 + brow + n * 16) * 64 + (kk ? cu1 : cu0)];
  };

  f32x4 acc[2][2][4][2] = {};
  bf16x8 af[4][2], af2[4][2], bl[2][2], bh[2][2];
  constexpr int NT = K >> 6;

  stA(0, 0, 0); stB(0, 0, 0); stB(0, 1, 0); stA(0, 1, 0);
  stA(1, 0, 1); stB(1, 0, 1); stB(1, 1, 1);
  asm volatile("s_waitcnt vmcnt(6)" ::: "memory");
  __builtin_amdgcn_s_barrier();

  auto tile_body = [&](int tt, int s1, int s2) {
    const int p = tt & 1;
#pragma unroll
    for (int m = 0; m < 4; ++m) { af[m][0] = ldA(p, 0, m, 0); af[m][1] = ldA(p, 0, m, 1); }
#pragma unroll
    for (int n = 0; n < 2; ++n) { bl[n][0] = ldB(p, 0, n, 0); bl[n][1] = ldB(p, 0, n, 1); }
    __builtin_amdgcn_sched_barrier(0);
#pragma unroll
    for (int n = 0; n < 2; ++n) { bh[n][0] = ldB(p, 1, n, 0); bh[n][1] = ldB(p, 1, n, 1); }
    __builtin_amdgcn_sched_barrier(0);
    if (s1) stA(tt + 1, 1, 1 - p);
    __builtin_amdgcn_sched_barrier(0);
    asm volatile("s_waitcnt lgkmcnt(4)" ::: "memory");
    __builtin_amdgcn_sched_barrier(0);
    __builtin_amdgcn_s_setprio(1);
    MFMA_QUAD(0, 0, af, bl)
    __builtin_amdgcn_s_setprio(0);
    __builtin_amdgcn_s_barrier();
#pragma unroll
    for (int m = 0; m < 4; ++m) { af2[m][0] = ldA(p, 1, m, 0); af2[m][1] = ldA(p, 1, m, 1); }
    __builtin_amdgcn_sched_barrier(0);
    if (s2) stA(tt + 2, 0, p);
    __builtin_amdgcn_sched_barrier(0);
    asm volatile("s_waitcnt lgkmcnt(8)" ::: "memory");
    __builtin_amdgcn_sched_barrier(0);
    __builtin_amdgcn_s_setprio(1);
    MFMA_QUAD(0, 1, af, bh)
    __builtin_amdgcn_s_setprio(0);
    __builtin_amdgcn_s_barrier();
    if (s2) { stB(tt + 2, 0, p); stB(tt + 2, 1, p); }
    __builtin_amdgcn_sched_barrier(0);
    asm volatile("s_waitcnt lgkmcnt(0)" ::: "memory");
    __builtin_amdgcn_sched_barrier(0);
    __builtin_amdgcn_s_setprio(1);
    MFMA_QUAD(1, 1, af2, bh)
    MFMA_QUAD(1, 0, af2, bl)
    __builtin_amdgcn_s_setprio(0);
    if (s2) { asm volatile("s_waitcnt vmcnt(6)" ::: "memory"); }
    else if (s1) { asm volatile("s_waitcnt vmcnt(0)" ::: "memory"); }
    __builtin_amdgcn_s_barrier();
  };

  for (int tt = 0; tt < NT - 2; ++tt) tile_body(tt, 1, 1);
  tile_body(NT - 2, 1, 0);
  tile_body(NT - 1, 0, 0);

  // ---------------- epilogue ----------------
  const int row0 = bm * 256 + wq * 64 + hi * 4;
  const int colw = bn * 256 + wn * 64;

  if (EPI == 1) {
#pragma unroll
    for (int Qm = 0; Qm < 2; ++Qm)
#pragma unroll
      for (int m = 0; m < 4; ++m)
#pragma unroll
        for (int r = 0; r < 4; ++r) {
          long row = row0 + Qm * 128 + m * 16 + r;
#pragma unroll
          for (int Qn = 0; Qn < 2; ++Qn)
#pragma unroll
            for (int n = 0; n < 2; ++n) {
              int col = colw + Qn * 32 + n * 16 + lr;
              Cf[row * LDC + col] = acc[Qm][Qn][m][n][r] + bias[col];
            }
        }
    return;
  }

  if (bn < 4) {
    // q: softmax over the wave's 64-col head segment -> qhat[bh][n][64]
    const int h = bn * 4 + wn;
#pragma unroll
    for (int Qm = 0; Qm < 2; ++Qm)
#pragma unroll
      for (int m = 0; m < 4; ++m)
#pragma unroll
        for (int r = 0; r < 4; ++r) {
          float pv[2][2];
          float mx = -1e30f;
#pragma unroll
          for (int Qn = 0; Qn < 2; ++Qn)
#pragma unroll
            for (int nn = 0; nn < 2; ++nn) {
              pv[Qn][nn] = acc[Qm][Qn][m][nn][r] * 0.125f;
              mx = fmaxf(mx, pv[Qn][nn]);
            }
#pragma unroll
          for (int off = 1; off < 16; off <<= 1) mx = fmaxf(mx, __shfl_xor(mx, off));
          float s = 0.f;
#pragma unroll
          for (int Qn = 0; Qn < 2; ++Qn)
#pragma unroll
            for (int nn = 0; nn < 2; ++nn) { pv[Qn][nn] = __expf(pv[Qn][nn] - mx); s += pv[Qn][nn]; }
#pragma unroll
          for (int off = 1; off < 16; off <<= 1) s += __shfl_xor(s, off);
          float inv = 1.0f / s;
          long row = row0 + Qm * 128 + m * 16 + r;
          long base = (((long)(row >> 13) * 16 + h) * NSEQ + (row & 8191)) * 64;
#pragma unroll
          for (int Qn = 0; Qn < 2; ++Qn)
#pragma unroll
            for (int nn = 0; nn < 2; ++nn)
              qh[base + Qn * 32 + nn * 16 + lr] = f2bf(pv[Qn][nn] * inv);
        }
  } else if (bn < 8) {
    // k: exp + per-batch column sums -> khat[bh][n][64]
    const int h = (bn - 4) * 4 + wn;
    float cs[2][2] = {};
#pragma unroll
    for (int Qm = 0; Qm < 2; ++Qm)
#pragma unroll
      for (int m = 0; m < 4; ++m)
#pragma unroll
        for (int r = 0; r < 4; ++r) {
          long row = row0 + Qm * 128 + m * 16 + r;
          long base = (((long)(row >> 13) * 16 + h) * NSEQ + (row & 8191)) * 64;
#pragma unroll
          for (int Qn = 0; Qn < 2; ++Qn)
#pragma unroll
            for (int nn = 0; nn < 2; ++nn) {
              float pe = __expf(acc[Qm][Qn][m][nn][r]);
              cs[Qn][nn] += pe;
              kh[base + Qn * 32 + nn * 16 + lr] = f2bf(pe);
            }
        }
#pragma unroll
    for (int Qn = 0; Qn < 2; ++Qn)
#pragma unroll
      for (int nn = 0; nn < 2; ++nn) {
        cs[Qn][nn] += __shfl_xor(cs[Qn][nn], 16);
        cs[Qn][nn] += __shfl_xor(cs[Qn][nn], 32);
      }
    if (lane < 16) {
      int b = bm >> 5;
#pragma unroll
      for (int Qn = 0; Qn < 2; ++Qn)
#pragma unroll
        for (int nn = 0; nn < 2; ++nn)
          atomicAdd(&S[b * DMODEL + h * 64 + Qn * 32 + nn * 16 + lane], cs[Qn][nn]);
    }
  } else {
    // v -> vhat [row][1024] contiguous
    const int vcol = (bn - 8) * 256 + wn * 64;
#pragma unroll
    for (int Qm = 0; Qm < 2; ++Qm)
#pragma unroll
      for (int m = 0; m < 4; ++m)
#pragma unroll
        for (int r = 0; r < 4; ++r) {
          long row = row0 + Qm * 128 + m * 16 + r;
#pragma unroll
          for (int Qn = 0; Qn < 2; ++Qn)
#pragma unroll
            for (int nn = 0; nn < 2; ++nn)
              vh[row * DMODEL + vcol + Qn * 32 + nn * 16 + lr] = f2bf(acc[Qm][Qn][m][nn][r]);
        }
  }
}

// ============ ctx partial via MFMA: ctx[bh][d][e] = sum_n q[n][d] k[n][e] ============
// grid (bh=64, nc=8), 256 thr / 4 waves. Stages 128 n-rows, transposed qT/kT [64][136].
__global__ __launch_bounds__(256) void k_ctx(const u16* __restrict__ qhat,
                                             const u16* __restrict__ khat,
                                             float* __restrict__ ctx_part) {
  __shared__ __align__(16) u16 smu[2 * 17408];  // buf{0,1} x (qT 8704 | kT 8704) u16
  const int bh = blockIdx.x, nc = blockIdx.y;
  const int t = threadIdx.x;
  const int lane = t & 63;
  const int ww = t >> 6;
  const int lr = lane & 15;
  const int hi = lane >> 4;

  const int isK = t >> 7;            // 0: stage q, 1: stage k
  const int u = t & 127;
  const int ng = u >> 3;             // 0..15 (n-group of 8)
  const int dc = u & 7;              // 0..7  (d-group of 8)
  const u16* srcm = (isK ? khat : qhat) + (long)bh * NSEQ * 64;

  f32x4 acc[4][4] = {};
  short8 v[8];

  auto load_stage = [&](int s) {
    long nb = (long)nc * 1024 + s * 128;
    const u16* src = srcm + (nb + ng * 8) * 64 + dc * 8;
#pragma unroll
    for (int i = 0; i < 8; ++i) v[i] = *(const short8*)(src + i * 64);
  };
  auto write_stage = [&](int s) {
    const int buf = s & 1;
    // dest row d = dc*8+j, col-group swizzled: (ng ^ dc)
    u16* dst0 = &smu[buf * 17408 + isK * 8704 + (dc * 8) * 136 + (ng ^ dc) * 8];
#pragma unroll
    for (int j = 0; j < 8; ++j) {
      short8 o;
#pragma unroll
      for (int i = 0; i < 8; ++i) o[i] = v[i][j];
      *(short8*)(dst0 + j * 136) = o;
    }
  };
  auto compute = [&](int s) {
    const int buf = s & 1;
    // wave ww reduces rows [ww*32, ww*32+32): n-group g = ww*4 + hi
    const int g = ww * 4 + hi;
    const u16* qb = &smu[buf * 17408];
    const u16* kb = qb + 8704;
    bf16x8 a[4], b[4];
#pragma unroll
    for (int dt = 0; dt < 4; ++dt) {
      int d = dt * 16 + lr;
      a[dt] = *(const bf16x8*)(qb + d * 136 + (g ^ ((d >> 3) & 7)) * 8);
    }
#pragma unroll
    for (int et = 0; et < 4; ++et) {
      int d = et * 16 + lr;
      b[et] = *(const bf16x8*)(kb + d * 136 + (g ^ ((d >> 3) & 7)) * 8);
    }
#pragma unroll
    for (int dt = 0; dt < 4; ++dt)
#pragma unroll
      for (int et = 0; et < 4; ++et)
        acc[dt][et] = __builtin_amdgcn_mfma_f32_16x16x32_bf16(a[dt], b[et], acc[dt][et], 0, 0, 0);
  };

  load_stage(0);
  write_stage(0);
  __syncthreads();
  for (int s = 0; s < 8; ++s) {
    if (s < 7) load_stage(s + 1);     // global loads early (hide under MFMA)
    compute(s);
    if (s < 7) write_stage(s + 1);    // LDS write late
    __syncthreads();
  }

  // cross-wave reduce: layout [ww][d4=16][e=64][r=4] f32 (reuse smu)
  float* smf = (float*)smu;
#pragma unroll
  for (int dt = 0; dt < 4; ++dt)
#pragma unroll
    for (int et = 0; et < 4; ++et)
      *(f32x4*)&smf[ww * 4096 + (dt * 4 + hi) * 256 + (et * 16 + lr) * 4] = acc[dt][et];
  __syncthreads();
  float* op = ctx_part + ((long)nc * 64 + bh) * 4096;
#pragma unroll
  for (int rep = 0; rep < 4; ++rep) {
    int p4 = rep * 1024 + t * 4;
    f32x4 sum = *(const f32x4*)&smf[p4];
    sum += *(const f32x4*)&smf[4096 + p4];
    sum += *(const f32x4*)&smf[8192 + p4];
    sum += *(const f32x4*)&smf[12288 + p4];
    *(f32x4*)&op[p4] = sum;
  }
}

// ---------------- reduce ctx partials (phys layout) -> ctx logical [bh][d][e] ----------------
__global__ __launch_bounds__(256) void k_cred(const float* __restrict__ ctx_part,
                                              float* __restrict__ ctx) {
  const int bh = blockIdx.x;
  const int p = blockIdx.y * 256 + threadIdx.x;  // 0..4095 phys
  float s = 0.f;
#pragma unroll
  for (int nc = 0; nc < 8; ++nc)
    s += ctx_part[((long)nc * 64 + bh) * 4096 + p];
  int d = (p >> 8) * 4 + (p & 3);
  int e = (p >> 2) & 63;
  ctx[(long)bh * 4096 + d * 64 + e] = s;
}

// ---------------- W2[b][eo][hd] = sum_e ctxn[b,h][d][e] * woutT[eo][h*64+e] ----------------
__global__ __launch_bounds__(256) void k_w2(const float* __restrict__ ctx,
                                            const float* __restrict__ S,
                                            const u16* __restrict__ woutT,
                                            u16* __restrict__ w2t) {
  __shared__ float cl[64][68];
  const int b = blockIdx.x, h = blockIdx.y, ec = blockIdx.z;
  const float* cp = ctx + ((long)(b * 16 + h)) * 4096;
  const float* Sp = S + b * DMODEL + h * 64;
  for (int i = threadIdx.x; i < 4096; i += 256) {
    int d = i >> 6, e = i & 63;
    cl[d][e] = cp[i] / Sp[e];
  }
  __syncthreads();
  const int eo = ec * 128 + (threadIdx.x & 127);
  const int dg = (threadIdx.x >> 7) * 32;
  const u16* wp = woutT + (long)eo * DMODEL + h * 64;
  float wv[64];
#pragma unroll
  for (int j = 0; j < 8; ++j) {
    short8 v8 = *(const short8*)(wp + j * 8);
#pragma unroll
    for (int i = 0; i < 8; ++i) wv[j * 8 + i] = bf2f((u16)v8[i]);
  }
  f32x4 w4[16];
#pragma unroll
  for (int j = 0; j < 16; ++j) w4[j] = *(const f32x4*)&wv[j * 4];
  u16* outp = w2t + ((long)b << 20) + (long)eo * DMODEL + h * 64;
  for (int d = dg; d < dg + 32; ++d) {
    f32x4 a = {0.f, 0.f, 0.f, 0.f};
#pragma unroll
    for (int j = 0; j < 16; ++j) {
      f32x4 c4 = *(const f32x4*)&cl[d][j * 4];
      a += c4 * w4[j];
    }
    outp[d] = f2bf(a[0] + a[1] + a[2] + a[3]);
  }
}

// ---------------- launch ----------------
extern "C" void kernel_launch(void* const* d_in, const int* in_sizes, int n_in,
                              void* d_out, int out_size, void* d_ws, size_t ws_size,
                              hipStream_t stream) {
  const float* x = (const float*)d_in[0];
  const float* w_qkv = (const float*)d_in[1];
  const float* w_out = (const float*)d_in[2];
  const float* b_out = (const float*)d_in[3];
  float* out = (float*)d_out;
  char* ws = (char*)d_ws;

  u16* xb      = (u16*)(ws + 0);                 // 64 MB
  u16* wqkvT   = (u16*)(ws + 67108864L);         // 6 MB
  u16* woutT   = (u16*)(ws + 73400320L);         // 2 MB
  u16* qhat    = (u16*)(ws + 75497472L);         // 64 MB
  u16* khat    = (u16*)(ws + 142606336L);        // 64 MB
  u16* vhat    = (u16*)(ws + 209715200L);        // 64 MB
  u16* w2t     = (u16*)(ws + 276824064L);        // 8 MB
  float* S     = (float*)(ws + 285212672L);      // 16 KB
  float* ctx   = (float*)(ws + 285229056L);      // 1 MB
  float* cpart = (float*)(ws + 286277632L);      // 8 MB

  hipMemsetAsync(S, 0, 16384, stream);

  k_convert<<<32768, 256, 0, stream>>>(x, xb, (long)MROWS * DMODEL);
  k_transpose<<<dim3(96, 32), dim3(32, 8), 0, stream>>>(w_qkv, wqkvT, DMODEL, QKVCOLS);
  k_transpose<<<dim3(32, 32), dim3(32, 8), 0, stream>>>(w_out, woutT, DMODEL, DMODEL);

  // qkv GEMM with fused q-softmax / k-exp epilogue -> qhat/khat/vhat
  k_gemm256<0, DMODEL, DMODEL, 12, QKVCOLS, 0L>
      <<<dim3((MROWS / 256) * (QKVCOLS / 256)), 512, 0, stream>>>(
      xb, wqkvT, nullptr, qhat, khat, vhat, nullptr, S);

  k_ctx<<<dim3(64, 8), 256, 0, stream>>>(qhat, khat, cpart);
  k_cred<<<dim3(64, 16), 256, 0, stream>>>(cpart, ctx);
  k_w2<<<dim3(4, 16, 8), 256, 0, stream>>>(ctx, S, woutT, w2t);

  // out GEMM: out = vhat x W2[b]^T + bias, fp32 store
  k_gemm256<1, DMODEL, DMODEL, 4, DMODEL, (long)DMODEL * DMODEL>
      <<<dim3((MROWS / 256) * (DMODEL / 256)), 512, 0, stream>>>(
      vhat, w2t, b_out, nullptr, nullptr, nullptr, out, nullptr);
}

// Round 8
// 331.673 us; speedup vs baseline: 1.9786x; 1.1762x over previous
//
#include <hip/hip_runtime.h>

typedef unsigned short u16;
typedef __attribute__((ext_vector_type(8))) short short8;
typedef __attribute__((ext_vector_type(4))) unsigned short u16x4;
typedef __attribute__((ext_vector_type(8))) __bf16 bf16x8;
typedef __attribute__((ext_vector_type(4))) float f32x4;

#define B_SZ 4
#define NSEQ 8192
#define DMODEL 1024
#define MROWS 32768
#define QKVCOLS 3072

static __device__ __forceinline__ u16 f2bf(float f) {
  unsigned u = __builtin_bit_cast(unsigned, f);
  u += 0x7fffu + ((u >> 16) & 1u);
  return (u16)(u >> 16);
}
static __device__ __forceinline__ float bf2f(u16 h) {
  return __builtin_bit_cast(float, ((unsigned)h) << 16);
}
static __device__ __forceinline__ void gload16(const u16* g, u16* l) {
  __builtin_amdgcn_global_load_lds(
      (const __attribute__((address_space(1))) unsigned*)g,
      (__attribute__((address_space(3))) unsigned*)l, 16, 0, 0);
}

// ---------------- fp32 -> bf16 convert ----------------
__global__ __launch_bounds__(256) void k_convert(const float* __restrict__ in,
                                                 u16* __restrict__ out, long n) {
  long i = ((long)blockIdx.x * 256 + threadIdx.x) * 4;
  if (i >= n) return;
  f32x4 v = *(const f32x4*)(in + i);
  u16x4 o;
  o[0] = f2bf(v[0]); o[1] = f2bf(v[1]); o[2] = f2bf(v[2]); o[3] = f2bf(v[3]);
  *(u16x4*)(out + i) = o;
}

// ---------------- wvb[i][k] = bf16(w_qkv[i][2048+k])  (1024x1024) ----------------
__global__ __launch_bounds__(256) void k_cv(const float* __restrict__ wq,
                                            u16* __restrict__ wvb) {
  int idx = (blockIdx.x * 256 + threadIdx.x) * 4;
  int i = idx >> 10, k = idx & 1023;
  f32x4 v = *(const f32x4*)(wq + (long)i * QKVCOLS + 2048 + k);
  u16x4 o;
  o[0] = f2bf(v[0]); o[1] = f2bf(v[1]); o[2] = f2bf(v[2]); o[3] = f2bf(v[3]);
  *(u16x4*)(wvb + idx) = o;
}

// ---------------- transpose fp32[R][C] -> bf16[C][R] ----------------
__global__ __launch_bounds__(256) void k_transpose(const float* __restrict__ in,
                                                   u16* __restrict__ out, int R, int C) {
  __shared__ float tile[32][33];
  int c0 = blockIdx.x * 32, r0 = blockIdx.y * 32;
  int tx = threadIdx.x, ty = threadIdx.y;  // (32, 8)
#pragma unroll
  for (int j = 0; j < 32; j += 8)
    tile[ty + j][tx] = in[(long)(r0 + ty + j) * C + c0 + tx];
  __syncthreads();
#pragma unroll
  for (int j = 0; j < 32; j += 8)
    out[(long)(c0 + ty + j) * R + r0 + tx] = f2bf(tile[tx][ty + j]);
}

// ============ 256x256 3-phase bf16 GEMM: C = A[M][K] * B^T[N][K] ============
// EPI 0: qk fused epilogue -> qhat/khat head-major [bh][n][64] (+softmax / exp+colsum)
// EPI 1: fp32 + bias to Cf
#define MFMA_QUAD(Qm, Qn, A_, B_)                                              \
  _Pragma("unroll") for (int m = 0; m < 4; ++m)                                \
  _Pragma("unroll") for (int n = 0; n < 2; ++n)                                \
    acc[Qm][Qn][m][n] = __builtin_amdgcn_mfma_f32_16x16x32_bf16(A_[m][1], B_[n][1], \
        __builtin_amdgcn_mfma_f32_16x16x32_bf16(A_[m][0], B_[n][0], acc[Qm][Qn][m][n], 0, 0, 0), 0, 0, 0);

template <int EPI, int K, int LDA, int NBN, int LDC, long BSTR>
__global__ __launch_bounds__(512, 2) void k_gemm256(
    const u16* __restrict__ A, const u16* __restrict__ Bp,
    const float* __restrict__ bias, u16* __restrict__ qh,
    u16* __restrict__ kh, float* __restrict__ Cf, float* __restrict__ S) {
  __shared__ __align__(16) u16 sm[65536];  // A0|A1|B0|B1, 16384 u16 each
  const int t = threadIdx.x;
  const int lane = t & 63;
  const int w = t >> 6;       // 0..7
  const int wq = w >> 2;      // row-half within quadrant
  const int wn = w & 3;       // col group
  const int lr = lane & 15;
  const int hi = lane >> 4;
  const int l3 = lane >> 3;

  // XCD swizzle + bm-group-of-8
  const int nwg = gridDim.x;
  const int bid = blockIdx.x;
  const int swz = (bid & 7) * (nwg >> 3) + (bid >> 3);
  const int per = 8 * NBN;
  const int grp = swz / per, rem = swz % per;
  const int bm = grp * 8 + (rem & 7);
  const int bn = rem / 8;

  const u16* B = Bp + (long)(bm >> 5) * BSTR;
  const int gcol = ((lane & 7) ^ l3) * 8;  // swizzled k-offset (elements)

  auto stA = [&](int tile, int half, int buf) {
    u16* dst = &sm[buf * 16384 + (half * 128 + w * 16) * 64];
    const u16* g = A + ((long)(bm * 256 + half * 128 + w * 16 + l3)) * LDA + tile * 64 + gcol;
    gload16(g, dst);
    gload16(g + 8 * (long)LDA, dst + 8 * 64);
  };
  auto stB = [&](int tile, int half, int buf) {
#pragma unroll
    for (int L = 0; L < 2; ++L) {
      int base = half * 128 + w * 16 + L * 8;  // LDS B row base
      int grow = bn * 256 + ((base >> 5) & 3) * 64 + half * 32 + (base & 31) + l3;
      const u16* g = B + (long)grow * K + tile * 64 + gcol;
      gload16(g, &sm[32768 + buf * 16384 + base * 64]);
    }
  };

  const int su = (lr & 7) << 3;
  const int cu0 = (hi * 8) ^ su;         // kk=0 swizzled col (u16 units)
  const int cu1 = (32 + hi * 8) ^ su;    // kk=1
  const int arow = wq * 64 + lr;
  const int brow = wn * 32 + lr;

  auto ldA = [&](int buf, int Qm, int m, int kk) -> bf16x8 {
    return *(const bf16x8*)&sm[buf * 16384 + (Qm * 128 + arow + m * 16) * 64 + (kk ? cu1 : cu0)];
  };
  auto ldB = [&](int buf, int Qn, int n, int kk) -> bf16x8 {
    return *(const bf16x8*)&sm[32768 + buf * 16384 + (Qn * 128 + brow + n * 16) * 64 + (kk ? cu1 : cu0)];
  };

  f32x4 acc[2][2][4][2] = {};
  bf16x8 af[4][2], af2[4][2], bl[2][2], bh[2][2];
  constexpr int NT = K >> 6;

  stA(0, 0, 0); stB(0, 0, 0); stB(0, 1, 0); stA(0, 1, 0);
  stA(1, 0, 1); stB(1, 0, 1); stB(1, 1, 1);
  asm volatile("s_waitcnt vmcnt(6)" ::: "memory");
  __builtin_amdgcn_s_barrier();

  auto tile_body = [&](int tt, int s1, int s2) {
    const int p = tt & 1;
#pragma unroll
    for (int m = 0; m < 4; ++m) { af[m][0] = ldA(p, 0, m, 0); af[m][1] = ldA(p, 0, m, 1); }
#pragma unroll
    for (int n = 0; n < 2; ++n) { bl[n][0] = ldB(p, 0, n, 0); bl[n][1] = ldB(p, 0, n, 1); }
    __builtin_amdgcn_sched_barrier(0);
#pragma unroll
    for (int n = 0; n < 2; ++n) { bh[n][0] = ldB(p, 1, n, 0); bh[n][1] = ldB(p, 1, n, 1); }
    __builtin_amdgcn_sched_barrier(0);
    if (s1) stA(tt + 1, 1, 1 - p);
    __builtin_amdgcn_sched_barrier(0);
    asm volatile("s_waitcnt lgkmcnt(4)" ::: "memory");
    __builtin_amdgcn_sched_barrier(0);
    __builtin_amdgcn_s_setprio(1);
    MFMA_QUAD(0, 0, af, bl)
    __builtin_amdgcn_s_setprio(0);
    __builtin_amdgcn_s_barrier();
#pragma unroll
    for (int m = 0; m < 4; ++m) { af2[m][0] = ldA(p, 1, m, 0); af2[m][1] = ldA(p, 1, m, 1); }
    __builtin_amdgcn_sched_barrier(0);
    if (s2) stA(tt + 2, 0, p);
    __builtin_amdgcn_sched_barrier(0);
    asm volatile("s_waitcnt lgkmcnt(8)" ::: "memory");
    __builtin_amdgcn_sched_barrier(0);
    __builtin_amdgcn_s_setprio(1);
    MFMA_QUAD(0, 1, af, bh)
    __builtin_amdgcn_s_setprio(0);
    __builtin_amdgcn_s_barrier();
    if (s2) { stB(tt + 2, 0, p); stB(tt + 2, 1, p); }
    __builtin_amdgcn_sched_barrier(0);
    asm volatile("s_waitcnt lgkmcnt(0)" ::: "memory");
    __builtin_amdgcn_sched_barrier(0);
    __builtin_amdgcn_s_setprio(1);
    MFMA_QUAD(1, 1, af2, bh)
    MFMA_QUAD(1, 0, af2, bl)
    __builtin_amdgcn_s_setprio(0);
    if (s2) { asm volatile("s_waitcnt vmcnt(6)" ::: "memory"); }
    else if (s1) { asm volatile("s_waitcnt vmcnt(0)" ::: "memory"); }
    __builtin_amdgcn_s_barrier();
  };

  for (int tt = 0; tt < NT - 2; ++tt) tile_body(tt, 1, 1);
  tile_body(NT - 2, 1, 0);
  tile_body(NT - 1, 0, 0);

  // ---------------- epilogue ----------------
  const int row0 = bm * 256 + wq * 64 + hi * 4;
  const int colw = bn * 256 + wn * 64;

  if (EPI == 1) {
#pragma unroll
    for (int Qm = 0; Qm < 2; ++Qm)
#pragma unroll
      for (int m = 0; m < 4; ++m)
#pragma unroll
        for (int r = 0; r < 4; ++r) {
          long row = row0 + Qm * 128 + m * 16 + r;
#pragma unroll
          for (int Qn = 0; Qn < 2; ++Qn)
#pragma unroll
            for (int n = 0; n < 2; ++n) {
              int col = colw + Qn * 32 + n * 16 + lr;
              Cf[row * LDC + col] = acc[Qm][Qn][m][n][r] + bias[col];
            }
        }
    return;
  }

  if (bn < 4) {
    // q: softmax over the wave's 64-col head segment -> qhat[bh][n][64]
    const int h = bn * 4 + wn;
#pragma unroll
    for (int Qm = 0; Qm < 2; ++Qm)
#pragma unroll
      for (int m = 0; m < 4; ++m)
#pragma unroll
        for (int r = 0; r < 4; ++r) {
          float pv[2][2];
          float mx = -1e30f;
#pragma unroll
          for (int Qn = 0; Qn < 2; ++Qn)
#pragma unroll
            for (int nn = 0; nn < 2; ++nn) {
              pv[Qn][nn] = acc[Qm][Qn][m][nn][r] * 0.125f;
              mx = fmaxf(mx, pv[Qn][nn]);
            }
#pragma unroll
          for (int off = 1; off < 16; off <<= 1) mx = fmaxf(mx, __shfl_xor(mx, off));
          float s = 0.f;
#pragma unroll
          for (int Qn = 0; Qn < 2; ++Qn)
#pragma unroll
            for (int nn = 0; nn < 2; ++nn) { pv[Qn][nn] = __expf(pv[Qn][nn] - mx); s += pv[Qn][nn]; }
#pragma unroll
          for (int off = 1; off < 16; off <<= 1) s += __shfl_xor(s, off);
          float inv = 1.0f / s;
          long row = row0 + Qm * 128 + m * 16 + r;
          long base = (((long)(row >> 13) * 16 + h) * NSEQ + (row & 8191)) * 64;
#pragma unroll
          for (int Qn = 0; Qn < 2; ++Qn)
#pragma unroll
            for (int nn = 0; nn < 2; ++nn)
              qh[base + Qn * 32 + nn * 16 + lr] = f2bf(pv[Qn][nn] * inv);
        }
  } else {
    // k: exp + per-batch column sums -> khat[bh][n][64]
    const int h = (bn - 4) * 4 + wn;
    float cs[2][2] = {};
#pragma unroll
    for (int Qm = 0; Qm < 2; ++Qm)
#pragma unroll
      for (int m = 0; m < 4; ++m)
#pragma unroll
        for (int r = 0; r < 4; ++r) {
          long row = row0 + Qm * 128 + m * 16 + r;
          long base = (((long)(row >> 13) * 16 + h) * NSEQ + (row & 8191)) * 64;
#pragma unroll
          for (int Qn = 0; Qn < 2; ++Qn)
#pragma unroll
            for (int nn = 0; nn < 2; ++nn) {
              float pe = __expf(acc[Qm][Qn][m][nn][r]);
              cs[Qn][nn] += pe;
              kh[base + Qn * 32 + nn * 16 + lr] = f2bf(pe);
            }
        }
#pragma unroll
    for (int Qn = 0; Qn < 2; ++Qn)
#pragma unroll
      for (int nn = 0; nn < 2; ++nn) {
        cs[Qn][nn] += __shfl_xor(cs[Qn][nn], 16);
        cs[Qn][nn] += __shfl_xor(cs[Qn][nn], 32);
      }
    if (lane < 16) {
      int b = bm >> 5;
#pragma unroll
      for (int Qn = 0; Qn < 2; ++Qn)
#pragma unroll
        for (int nn = 0; nn < 2; ++nn)
          atomicAdd(&S[b * DMODEL + h * 64 + Qn * 32 + nn * 16 + lane], cs[Qn][nn]);
    }
  }
}

// ============ ctx partial via MFMA: ctx[bh][d][e] = sum_n q[n][d] k[n][e] ============
__global__ __launch_bounds__(256) void k_ctx(const u16* __restrict__ qhat,
                                             const u16* __restrict__ khat,
                                             float* __restrict__ ctx_part) {
  __shared__ __align__(16) u16 smu[2 * 17408];  // buf{0,1} x (qT 8704 | kT 8704) u16
  const int bh = blockIdx.x, nc = blockIdx.y;
  const int t = threadIdx.x;
  const int lane = t & 63;
  const int ww = t >> 6;
  const int lr = lane & 15;
  const int hi = lane >> 4;

  const int isK = t >> 7;
  const int u = t & 127;
  const int ng = u >> 3;
  const int dc = u & 7;
  const u16* srcm = (isK ? khat : qhat) + (long)bh * NSEQ * 64;

  f32x4 acc[4][4] = {};
  short8 v[8];

  auto load_stage = [&](int s) {
    long nb = (long)nc * 1024 + s * 128;
    const u16* src = srcm + (nb + ng * 8) * 64 + dc * 8;
#pragma unroll
    for (int i = 0; i < 8; ++i) v[i] = *(const short8*)(src + i * 64);
  };
  auto write_stage = [&](int s) {
    const int buf = s & 1;
    u16* dst0 = &smu[buf * 17408 + isK * 8704 + (dc * 8) * 136 + (ng ^ dc) * 8];
#pragma unroll
    for (int j = 0; j < 8; ++j) {
      short8 o;
#pragma unroll
      for (int i = 0; i < 8; ++i) o[i] = v[i][j];
      *(short8*)(dst0 + j * 136) = o;
    }
  };
  auto compute = [&](int s) {
    const int buf = s & 1;
    const int g = ww * 4 + hi;
    const u16* qb = &smu[buf * 17408];
    const u16* kb = qb + 8704;
    bf16x8 a[4], b[4];
#pragma unroll
    for (int dt = 0; dt < 4; ++dt) {
      int d = dt * 16 + lr;
      a[dt] = *(const bf16x8*)(qb + d * 136 + (g ^ ((d >> 3) & 7)) * 8);
    }
#pragma unroll
    for (int et = 0; et < 4; ++et) {
      int d = et * 16 + lr;
      b[et] = *(const bf16x8*)(kb + d * 136 + (g ^ ((d >> 3) & 7)) * 8);
    }
#pragma unroll
    for (int dt = 0; dt < 4; ++dt)
#pragma unroll
      for (int et = 0; et < 4; ++et)
        acc[dt][et] = __builtin_amdgcn_mfma_f32_16x16x32_bf16(a[dt], b[et], acc[dt][et], 0, 0, 0);
  };

  load_stage(0);
  write_stage(0);
  __syncthreads();
  for (int s = 0; s < 8; ++s) {
    if (s < 7) load_stage(s + 1);
    compute(s);
    if (s < 7) write_stage(s + 1);
    __syncthreads();
  }

  float* smf = (float*)smu;
#pragma unroll
  for (int dt = 0; dt < 4; ++dt)
#pragma unroll
    for (int et = 0; et < 4; ++et)
      *(f32x4*)&smf[ww * 4096 + (dt * 4 + hi) * 256 + (et * 16 + lr) * 4] = acc[dt][et];
  __syncthreads();
  float* op = ctx_part + ((long)nc * 64 + bh) * 4096;
#pragma unroll
  for (int rep = 0; rep < 4; ++rep) {
    int p4 = rep * 1024 + t * 4;
    f32x4 sum = *(const f32x4*)&smf[p4];
    sum += *(const f32x4*)&smf[4096 + p4];
    sum += *(const f32x4*)&smf[8192 + p4];
    sum += *(const f32x4*)&smf[12288 + p4];
    *(f32x4*)&op[p4] = sum;
  }
}

// ---------------- reduce partials + normalize by S -> ctxn bf16 [bh][d][e] ----------------
__global__ __launch_bounds__(256) void k_cred(const float* __restrict__ ctx_part,
                                              const float* __restrict__ S,
                                              u16* __restrict__ ctxn) {
  const int bh = blockIdx.x;
  const int b = bh >> 4, h = bh & 15;
  const int p = blockIdx.y * 256 + threadIdx.x;  // 0..4095 phys
  float s = 0.f;
#pragma unroll
  for (int nc = 0; nc < 8; ++nc)
    s += ctx_part[((long)nc * 64 + bh) * 4096 + p];
  int d = (p >> 8) * 4 + (p & 3);
  int e = (p >> 2) & 63;
  ctxn[(long)bh * 4096 + d * 64 + e] = f2bf(s / S[b * DMODEL + h * 64 + e]);
}

// ---------------- CtT[b][eo][h64+d] = sum_e woutT[eo][h64+e] * ctxn[bh][d][e] ----------------
// grid (4, 16), 256 thr / 4 waves; wave ww covers eo rows [ww*256, ww*256+256)
__global__ __launch_bounds__(256) void k_ct(const u16* __restrict__ woutT,
                                            const u16* __restrict__ ctxn,
                                            u16* __restrict__ ctT) {
  __shared__ __align__(16) u16 cb[64 * 72];
  const int b = blockIdx.x, h = blockIdx.y;
  const int t = threadIdx.x, lane = t & 63, ww = t >> 6;
  const int lr = lane & 15, hi = lane >> 4;
  {
    const u16* src = ctxn + ((long)(b * 16 + h)) * 4096 + t * 16;
    int row = t >> 2, col = (t & 3) * 16;
    *(short8*)(cb + row * 72 + col) = *(const short8*)src;
    *(short8*)(cb + row * 72 + col + 8) = *(const short8*)(src + 8);
  }
  __syncthreads();
  bf16x8 bfrag[4][2];
#pragma unroll
  for (int n = 0; n < 4; ++n)
#pragma unroll
    for (int kk = 0; kk < 2; ++kk)
      bfrag[n][kk] = *(const bf16x8*)(cb + (n * 16 + lr) * 72 + kk * 32 + hi * 8);
  const int row0 = ww * 256;
  u16* outp = ctT + ((long)b * 1024) * 1024 + (long)h * 64;
#pragma unroll
  for (int m = 0; m < 16; ++m) {
    int arow = row0 + m * 16 + lr;
    const u16* ap = woutT + (long)arow * DMODEL + h * 64;
    bf16x8 a0 = *(const bf16x8*)(ap + hi * 8);
    bf16x8 a1 = *(const bf16x8*)(ap + 32 + hi * 8);
    f32x4 accr[4] = {};
#pragma unroll
    for (int n = 0; n < 4; ++n)
      accr[n] = __builtin_amdgcn_mfma_f32_16x16x32_bf16(a1, bfrag[n][1],
                __builtin_amdgcn_mfma_f32_16x16x32_bf16(a0, bfrag[n][0], accr[n], 0, 0, 0), 0, 0, 0);
#pragma unroll
    for (int n = 0; n < 4; ++n)
#pragma unroll
      for (int r = 0; r < 4; ++r)
        outp[(long)(row0 + m * 16 + hi * 4 + r) * DMODEL + n * 16 + lr] = f2bf(accr[n][r]);
  }
}

// ---------------- 128x128 bf16 GEMM (round-1 structure): C[M][N] = A[M][K]*B^T[N][K], bf16 out
__global__ __launch_bounds__(256) void k_wc(const u16* __restrict__ A,
                                            const u16* __restrict__ B,
                                            u16* __restrict__ Cb) {
  __shared__ __align__(16) u16 As[128 * 32];
  __shared__ __align__(16) u16 Bs[128 * 32];
  const int K = 1024, ldc = 1024;
  const int t = threadIdx.x;
  const int lane = t & 63;
  const int w = t >> 6;
  const int wm = w >> 1, wn = w & 1;
  const long bm = blockIdx.x, bn = blockIdx.y;

  f32x4 acc[4][4] = {};

  const u16* Ag = A + bm * 128 * (long)K;
  const u16* Bg = B + bn * 128 * (long)K;
  const int r0 = t >> 2;
  const int s0 = (t & 3) * 8;
  const int ko = (lane >> 4) * 8;
  const int lr = lane & 15;

  for (int kt = 0; kt < K; kt += 32) {
    short8 a0 = *(const short8*)(Ag + (long)r0 * K + kt + s0);
    short8 a1 = *(const short8*)(Ag + (long)(r0 + 64) * K + kt + s0);
    short8 b0 = *(const short8*)(Bg + (long)r0 * K + kt + s0);
    short8 b1 = *(const short8*)(Bg + (long)(r0 + 64) * K + kt + s0);
    __syncthreads();
    *(short8*)(As + r0 * 32 + s0) = a0;
    *(short8*)(As + (r0 + 64) * 32 + s0) = a1;
    *(short8*)(Bs + r0 * 32 + s0) = b0;
    *(short8*)(Bs + (r0 + 64) * 32 + s0) = b1;
    __syncthreads();
    bf16x8 af[4], bfr[4];
#pragma unroll
    for (int m = 0; m < 4; ++m)
      af[m] = *(const bf16x8*)(As + (wm * 64 + m * 16 + lr) * 32 + ko);
#pragma unroll
    for (int n = 0; n < 4; ++n)
      bfr[n] = *(const bf16x8*)(Bs + (wn * 64 + n * 16 + lr) * 32 + ko);
#pragma unroll
    for (int m = 0; m < 4; ++m)
#pragma unroll
      for (int n = 0; n < 4; ++n)
        acc[m][n] = __builtin_amdgcn_mfma_f32_16x16x32_bf16(af[m], bfr[n], acc[m][n], 0, 0, 0);
  }

  const int row_base = (int)bm * 128 + wm * 64 + (lane >> 4) * 4;
  const int col_base = (int)bn * 128 + wn * 64 + lr;
#pragma unroll
  for (int m = 0; m < 4; ++m)
#pragma unroll
    for (int n = 0; n < 4; ++n)
#pragma unroll
      for (int r = 0; r < 4; ++r)
        Cb[(long)(row_base + m * 16 + r) * ldc + col_base + n * 16] = f2bf(acc[m][n][r]);
}

// ---------------- launch ----------------
extern "C" void kernel_launch(void* const* d_in, const int* in_sizes, int n_in,
                              void* d_out, int out_size, void* d_ws, size_t ws_size,
                              hipStream_t stream) {
  const float* x = (const float*)d_in[0];
  const float* w_qkv = (const float*)d_in[1];
  const float* w_out = (const float*)d_in[2];
  const float* b_out = (const float*)d_in[3];
  float* out = (float*)d_out;
  char* ws = (char*)d_ws;

  u16* xb      = (u16*)(ws + 0);                 // 64 MB
  u16* wqkvT   = (u16*)(ws + 67108864L);         // 6 MB (qk cols only used)
  u16* woutT   = (u16*)(ws + 73400320L);         // 2 MB
  u16* wvb     = (u16*)(ws + 75497472L);         // 2 MB
  u16* qhat    = (u16*)(ws + 77594624L);         // 64 MB
  u16* khat    = (u16*)(ws + 144703488L);        // 64 MB
  float* S     = (float*)(ws + 211812352L);      // 16 KB
  u16* ctxn    = (u16*)(ws + 211828736L);        // 512 KB
  float* cpart = (float*)(ws + 212353024L);      // 8 MB
  u16* ctT     = (u16*)(ws + 220741632L);        // 8 MB
  u16* wcT     = (u16*)(ws + 229130240L);        // 8 MB

  hipMemsetAsync(S, 0, 16384, stream);

  k_convert<<<32768, 256, 0, stream>>>(x, xb, (long)MROWS * DMODEL);
  k_cv<<<1024, 256, 0, stream>>>(w_qkv, wvb);
  k_transpose<<<dim3(64, 32), dim3(32, 8), 0, stream>>>(w_qkv, wqkvT, DMODEL, QKVCOLS);
  k_transpose<<<dim3(32, 32), dim3(32, 8), 0, stream>>>(w_out, woutT, DMODEL, DMODEL);

  // qk GEMM (N=2048) with fused q-softmax / k-exp epilogue -> qhat/khat
  k_gemm256<0, DMODEL, DMODEL, 8, QKVCOLS, 0L>
      <<<dim3((MROWS / 256) * (2048 / 256)), 512, 0, stream>>>(
      xb, wqkvT, nullptr, qhat, khat, nullptr, S);

  k_ctx<<<dim3(64, 8), 256, 0, stream>>>(qhat, khat, cpart);
  k_cred<<<dim3(64, 16), 256, 0, stream>>>(cpart, S, ctxn);
  k_ct<<<dim3(4, 16), 256, 0, stream>>>(woutT, ctxn, ctT);
  // WcT[b] = CtT[b] @ Wv^T  (M=4096 stacked, N=1024, K=1024)
  k_wc<<<dim3(32, 8), 256, 0, stream>>>(ctT, wvb, wcT);

  // out GEMM: out = xb x WcT[b]^T + bias, fp32 store
  k_gemm256<1, DMODEL, DMODEL, 4, DMODEL, (long)DMODEL * DMODEL>
      <<<dim3((MROWS / 256) * (DMODEL / 256)), 512, 0, stream>>>(
      xb, wcT, b_out, nullptr, nullptr, out, nullptr);
}